// Round 1
// baseline (363.267 us; speedup 1.0000x reference)
//
#include <hip/hip_runtime.h>
#include <hip/hip_bf16.h>

#define S_LEN 4096
#define HDIM  64
#define NH    8

typedef short s16x8 __attribute__((ext_vector_type(8)));
typedef float f32x16 __attribute__((ext_vector_type(16)));

union FragU {
    s16x8 v;
    unsigned int u[4];
    unsigned short h[8];
};

static __device__ __forceinline__ unsigned int pack2_bf16(float a, float b) {
    __hip_bfloat162 h2 = __float22bfloat162_rn(float2{a, b});
    union { __hip_bfloat162 h; unsigned int u; } cv;
    cv.h = h2;
    return cv.u;
}

static __device__ __forceinline__ unsigned short to_bf16(float a) {
    __hip_bfloat16 h = __float2bfloat16(a);
    union { __hip_bfloat16 h; unsigned short u; } cv;
    cv.h = h;
    return cv.u;
}

// log2(e)/64 : folds both the 1/hd score scale and the exp->exp2 conversion into Q
#define Q_PRESCALE 0.022542110f
// log2(1e8)/128
#define FREQ_L2 0.20762050593046f

// ---------------------------------------------------------------------------
// Kernel 1: C = X @ W^T + b, rotary for Q/K, bf16 pack into (bh, s, d) layout.
// grid (4, 64, 3), block 256. 128x128 block tile, 4 waves x (2x2 of 32x32).
// ---------------------------------------------------------------------------
__global__ __launch_bounds__(256) void qkv_rope_proj(
    const float* __restrict__ q_in, const float* __restrict__ k_in,
    const float* __restrict__ v_in,
    const float* __restrict__ Wq, const float* __restrict__ bq,
    const float* __restrict__ Wk, const float* __restrict__ bk,
    const float* __restrict__ Wv, const float* __restrict__ bv,
    unsigned short* __restrict__ ws)
{
    const int z = blockIdx.z;
    const float* X    = (z == 0) ? q_in : ((z == 1) ? k_in : v_in);
    const float* W    = (z == 0) ? Wq   : ((z == 1) ? Wk   : Wv);
    const float* bias = (z == 0) ? bq   : ((z == 1) ? bk   : bv);
    unsigned short* dst = ws + (size_t)z * (size_t)(2 * NH * S_LEN * HDIM);

    const int tid  = threadIdx.x;
    const int wv   = tid >> 6;
    const int lane = tid & 63;
    const int c31  = lane & 31;
    const int hi   = lane >> 5;
    const int wm   = wv >> 1, wn = wv & 1;

    const int m0 = blockIdx.y * 128 + wm * 64;
    const int n0 = blockIdx.x * 128 + wn * 64;

    f32x16 acc[2][2];
    #pragma unroll
    for (int a = 0; a < 2; ++a)
    #pragma unroll
    for (int b = 0; b < 2; ++b)
    #pragma unroll
    for (int r = 0; r < 16; ++r) acc[a][b][r] = 0.f;

    for (int kc = 0; kc < 32; ++kc) {
        const int kofs = kc * 16 + hi * 8;
        FragU a_f[2], b_f[2];
        #pragma unroll
        for (int mt = 0; mt < 2; ++mt) {
            const float4* p = (const float4*)(X + (size_t)(m0 + mt * 32 + c31) * 512 + kofs);
            float4 x0 = p[0], x1 = p[1];
            a_f[mt].u[0] = pack2_bf16(x0.x, x0.y);
            a_f[mt].u[1] = pack2_bf16(x0.z, x0.w);
            a_f[mt].u[2] = pack2_bf16(x1.x, x1.y);
            a_f[mt].u[3] = pack2_bf16(x1.z, x1.w);
        }
        #pragma unroll
        for (int nt = 0; nt < 2; ++nt) {
            const float4* p = (const float4*)(W + (size_t)(n0 + nt * 32 + c31) * 512 + kofs);
            float4 x0 = p[0], x1 = p[1];
            b_f[nt].u[0] = pack2_bf16(x0.x, x0.y);
            b_f[nt].u[1] = pack2_bf16(x0.z, x0.w);
            b_f[nt].u[2] = pack2_bf16(x1.x, x1.y);
            b_f[nt].u[3] = pack2_bf16(x1.z, x1.w);
        }
        #pragma unroll
        for (int mt = 0; mt < 2; ++mt)
        #pragma unroll
        for (int nt = 0; nt < 2; ++nt)
            acc[mt][nt] = __builtin_amdgcn_mfma_f32_32x32x16_bf16(
                a_f[mt].v, b_f[nt].v, acc[mt][nt], 0, 0, 0);
    }

    // epilogue: bias (+rotary for z<2, +prescale for z==0), bf16, head layout
    #pragma unroll
    for (int nt = 0; nt < 2; ++nt) {
        const int o = n0 + nt * 32 + c31;          // output channel
        const float bv_ = bias[o];
        float freq = 0.f;
        int sel = 0;
        if (z < 2) {
            freq = exp2f(-(float)(o >> 2) * FREQ_L2);
            sel  = (o >> 1) & 1;
        }
        #pragma unroll
        for (int mt = 0; mt < 2; ++mt) {
            #pragma unroll
            for (int r = 0; r < 16; ++r) {
                const int m = m0 + mt * 32 + (r & 3) + 8 * (r >> 2) + 4 * hi;
                const int s = m & 4095;
                float val = acc[mt][nt][r] + bv_;
                float res;
                if (z < 2) {
                    const float pos = (float)(sel ? (s & 63) : (s >> 6));
                    float sv, cv_;
                    __sincosf(pos * freq, &sv, &cv_);
                    const float partner = __shfl_xor(val, 1);
                    const float sg = (o & 1) ? sv : -sv;     // even: xr*c - xi*s ; odd: xr*s + xi*c
                    res = fmaf(partner, sg, val * cv_);
                    if (z == 0) res *= Q_PRESCALE;
                } else {
                    res = val;
                }
                const int b  = m >> 12;
                const int bh = b * NH + (o >> 6);
                dst[(size_t)bh * (S_LEN * HDIM) + (size_t)s * HDIM + (o & 63)] = to_bf16(res);
            }
        }
    }
}

// ---------------------------------------------------------------------------
// Kernel 2: flash attention, S^T trick, streaming softmax (no max-sub),
// barrier-free main loop (waves own disjoint KV tiles), end merge via LDS.
// grid (64, 16), block 256. BM=64 (2 q-tiles/wave), BN=32 per wave-iter.
// ---------------------------------------------------------------------------
__global__ __launch_bounds__(256) void flash_attn_st(
    const unsigned short* __restrict__ ws, float* __restrict__ out)
{
    __shared__ __align__(16) unsigned char smem[33792];
    unsigned short* sVt_all = (unsigned short*)smem;          // 4 waves * 2560 ushorts (stride 40)
    float* sOb = (float*)smem;                                 // 2 * 4096 floats (reused post-loop)
    float* sL  = (float*)(smem + 32768);                       // 4*2*32 floats

    const unsigned short* Qws = ws;
    const unsigned short* Kws = ws + (size_t)4194304;
    const unsigned short* Vws = ws + (size_t)8388608;

    const int tid  = threadIdx.x;
    const int wv   = tid >> 6;
    const int lane = tid & 63;
    const int c31  = lane & 31;
    const int hi   = lane >> 5;
    const int q0   = blockIdx.x * 64;
    const int bh   = blockIdx.y;

    const unsigned short* Qb = Qws + (size_t)bh * (S_LEN * HDIM);
    const unsigned short* Kb = Kws + (size_t)bh * (S_LEN * HDIM);
    const unsigned short* Vb = Vws + (size_t)bh * (S_LEN * HDIM);

    unsigned short* sVt = sVt_all + wv * 2560;

    // Q B-frags: B[k][n] = Q[q0+qt*32+n][kc*16 + k], n=c31, k=hi*8+j
    s16x8 qf[2][4];
    #pragma unroll
    for (int qt = 0; qt < 2; ++qt)
    #pragma unroll
    for (int kc = 0; kc < 4; ++kc)
        qf[qt][kc] = *(const s16x8*)(Qb + (size_t)(q0 + qt * 32 + c31) * HDIM + kc * 16 + hi * 8);

    f32x16 o_acc[2][2];                   // [d-tile][q-tile], O^T layout
    #pragma unroll
    for (int a = 0; a < 2; ++a)
    #pragma unroll
    for (int b = 0; b < 2; ++b)
    #pragma unroll
    for (int r = 0; r < 16; ++r) o_acc[a][b][r] = 0.f;
    float l_acc[2] = {0.f, 0.f};

    const int vs0 = (lane & 15) * 2;      // kv pair base for V staging
    const int vd0 = (lane >> 4) * 8;      // d octet base

    for (int it = 0; it < 32; ++it) {
        const int kv0 = (it * 4 + wv) * 32;

        // ---- stage V^T into LDS (Vt[d][kv], stride 40) ----
        #pragma unroll
        for (int pass = 0; pass < 2; ++pass) {
            const int d0 = vd0 + pass * 32;
            const unsigned short* vg = Vb + (size_t)(kv0 + vs0) * HDIM + d0;
            FragU v0, v1;
            v0.v = *(const s16x8*)vg;
            v1.v = *(const s16x8*)(vg + HDIM);
            #pragma unroll
            for (int j = 0; j < 8; ++j) {
                unsigned int pk = (unsigned int)v0.h[j] | ((unsigned int)v1.h[j] << 16);
                *(unsigned int*)(sVt + (d0 + j) * 40 + vs0) = pk;
            }
        }

        // ---- K A-frags direct from global: A[m][k] = K[kv0+m][kc*16+k] ----
        s16x8 ka[4];
        #pragma unroll
        for (int kc = 0; kc < 4; ++kc)
            ka[kc] = *(const s16x8*)(Kb + (size_t)(kv0 + c31) * HDIM + kc * 16 + hi * 8);

        // ---- S^T = K * Q^T  (rows=kv, cols=q) ----
        f32x16 st[2];
        #pragma unroll
        for (int qt = 0; qt < 2; ++qt) {
            #pragma unroll
            for (int r = 0; r < 16; ++r) st[qt][r] = 0.f;
            #pragma unroll
            for (int kc = 0; kc < 4; ++kc)
                st[qt] = __builtin_amdgcn_mfma_f32_32x32x16_bf16(ka[kc], qf[qt][kc], st[qt], 0, 0, 0);
        }

        // ---- p = exp2(s) (scale pre-folded into Q), l accumulate, bf16 pack ----
        unsigned int up[2][8];
        #pragma unroll
        for (int qt = 0; qt < 2; ++qt) {
            float ls = 0.f;
            #pragma unroll
            for (int qq = 0; qq < 8; ++qq) {
                float p0 = exp2f(st[qt][2 * qq]);
                float p1 = exp2f(st[qt][2 * qq + 1]);
                ls += p0 + p1;
                up[qt][qq] = pack2_bf16(p0, p1);
            }
            l_acc[qt] += ls;
        }

        // ---- V^T A-frags from LDS ----
        s16x8 va[2][2];
        #pragma unroll
        for (int dt = 0; dt < 2; ++dt)
        #pragma unroll
        for (int k2 = 0; k2 < 2; ++k2)
            va[dt][k2] = *(const s16x8*)(sVt + (dt * 32 + c31) * 40 + k2 * 16 + hi * 8);

        // ---- O^T += V^T * P^T ; P^T B-frag assembled via shfl_xor(32) ----
        #pragma unroll
        for (int qt = 0; qt < 2; ++qt) {
            #pragma unroll
            for (int k2 = 0; k2 < 2; ++k2) {
                const unsigned int a0 = up[qt][4 * k2 + 0];
                const unsigned int a1 = up[qt][4 * k2 + 1];
                const unsigned int a2 = up[qt][4 * k2 + 2];
                const unsigned int a3 = up[qt][4 * k2 + 3];
                const unsigned int s0 = (unsigned int)__shfl_xor((int)(hi ? a0 : a2), 32);
                const unsigned int s1 = (unsigned int)__shfl_xor((int)(hi ? a1 : a3), 32);
                FragU pb;
                pb.u[0] = hi ? s0 : a0;
                pb.u[1] = hi ? s1 : a1;
                pb.u[2] = hi ? a2 : s0;
                pb.u[3] = hi ? a3 : s1;
                #pragma unroll
                for (int dt = 0; dt < 2; ++dt)
                    o_acc[dt][qt] = __builtin_amdgcn_mfma_f32_32x32x16_bf16(
                        va[dt][k2], pb.v, o_acc[dt][qt], 0, 0, 0);
            }
        }
    }

    // ---- merge partials across the 4 waves ----
    {
        float l0 = l_acc[0] + __shfl_xor(l_acc[0], 32);
        float l1 = l_acc[1] + __shfl_xor(l_acc[1], 32);
        if (lane < 32) {
            sL[(wv * 2 + 0) * 32 + lane] = l0;
            sL[(wv * 2 + 1) * 32 + lane] = l1;
        }
    }
    __syncthreads();

    if (wv == 1 || wv == 2) {
        float* buf = sOb + (wv - 1) * 4096;
        #pragma unroll
        for (int dt = 0; dt < 2; ++dt)
        #pragma unroll
        for (int qt = 0; qt < 2; ++qt)
        #pragma unroll
        for (int r = 0; r < 16; ++r) {
            const int d = dt * 32 + (r & 3) + 8 * (r >> 2) + 4 * hi;
            buf[d * 64 + qt * 32 + c31] = o_acc[dt][qt][r];
        }
    }
    __syncthreads();
    if (wv == 0 || wv == 3) {
        const float* buf = sOb + ((wv == 0) ? 0 : 4096);
        #pragma unroll
        for (int dt = 0; dt < 2; ++dt)
        #pragma unroll
        for (int qt = 0; qt < 2; ++qt)
        #pragma unroll
        for (int r = 0; r < 16; ++r) {
            const int d = dt * 32 + (r & 3) + 8 * (r >> 2) + 4 * hi;
            o_acc[dt][qt][r] += buf[d * 64 + qt * 32 + c31];
        }
    }
    __syncthreads();
    if (wv == 3) {
        #pragma unroll
        for (int dt = 0; dt < 2; ++dt)
        #pragma unroll
        for (int qt = 0; qt < 2; ++qt)
        #pragma unroll
        for (int r = 0; r < 16; ++r) {
            const int d = dt * 32 + (r & 3) + 8 * (r >> 2) + 4 * hi;
            sOb[d * 64 + qt * 32 + c31] = o_acc[dt][qt][r];
        }
    }
    __syncthreads();
    if (wv == 0) {
        #pragma unroll
        for (int dt = 0; dt < 2; ++dt)
        #pragma unroll
        for (int qt = 0; qt < 2; ++qt)
        #pragma unroll
        for (int r = 0; r < 16; ++r) {
            const int d = dt * 32 + (r & 3) + 8 * (r >> 2) + 4 * hi;
            o_acc[dt][qt][r] += sOb[d * 64 + qt * 32 + c31];
        }
        const int b  = bh >> 3;
        const int hh = bh & 7;
        #pragma unroll
        for (int qt = 0; qt < 2; ++qt) {
            const float lsum = sL[(0 * 2 + qt) * 32 + c31] + sL[(1 * 2 + qt) * 32 + c31]
                             + sL[(2 * 2 + qt) * 32 + c31] + sL[(3 * 2 + qt) * 32 + c31];
            const float rinv = 1.f / lsum;
            const int s = q0 + qt * 32 + c31;
            float* orow = out + ((size_t)b * S_LEN + s) * 512 + hh * 64;
            #pragma unroll
            for (int dt = 0; dt < 2; ++dt) {
                #pragma unroll
                for (int g = 0; g < 4; ++g) {
                    float4 vv;
                    vv.x = o_acc[dt][qt][4 * g + 0] * rinv;
                    vv.y = o_acc[dt][qt][4 * g + 1] * rinv;
                    vv.z = o_acc[dt][qt][4 * g + 2] * rinv;
                    vv.w = o_acc[dt][qt][4 * g + 3] * rinv;
                    *(float4*)(orow + dt * 32 + 8 * g + 4 * hi) = vv;
                }
            }
        }
    }
}

extern "C" void kernel_launch(void* const* d_in, const int* in_sizes, int n_in,
                              void* d_out, int out_size, void* d_ws, size_t ws_size,
                              hipStream_t stream) {
    (void)in_sizes; (void)n_in; (void)out_size; (void)ws_size;
    const float* q_in = (const float*)d_in[0];
    const float* k_in = (const float*)d_in[1];
    const float* v_in = (const float*)d_in[2];
    const float* Wq   = (const float*)d_in[3];
    const float* bq   = (const float*)d_in[4];
    const float* Wk   = (const float*)d_in[5];
    const float* bk   = (const float*)d_in[6];
    const float* Wv   = (const float*)d_in[7];
    const float* bv   = (const float*)d_in[8];
    unsigned short* ws = (unsigned short*)d_ws;
    float* out = (float*)d_out;

    qkv_rope_proj<<<dim3(4, 64, 3), 256, 0, stream>>>(
        q_in, k_in, v_in, Wq, bq, Wk, bk, Wv, bv, ws);
    flash_attn_st<<<dim3(64, 16), 256, 0, stream>>>(ws, out);
}

// Round 2
// 315.779 us; speedup vs baseline: 1.1504x; 1.1504x over previous
//
#include <hip/hip_runtime.h>
#include <hip/hip_bf16.h>

#define S_LEN 4096
#define HDIM  64
#define NH    8

// ws layout (ushort units) for the big-ws path
#define XBF_OFF   0            // 3 * 4194304  (bf16 X for q,k,v inputs)
#define WBF_OFF   12582912     // 3 * 262144   (bf16 W)
#define QKV_OFF   13369344     // 3 * 4194304  (rope'd Q,K,V in (bh,s,d))
#define WS_NEED_BYTES 51904512ull

typedef short s16x8 __attribute__((ext_vector_type(8)));
typedef float f32x16 __attribute__((ext_vector_type(16)));

union FragU {
    s16x8 v;
    unsigned int u[4];
    unsigned short h[8];
};

static __device__ __forceinline__ unsigned int pack2_bf16(float a, float b) {
    __hip_bfloat162 h2 = __float22bfloat162_rn(float2{a, b});
    union { __hip_bfloat162 h; unsigned int u; } cv;
    cv.h = h2;
    return cv.u;
}

static __device__ __forceinline__ unsigned short to_bf16(float a) {
    __hip_bfloat16 h = __float2bfloat16(a);
    union { __hip_bfloat16 h; unsigned short u; } cv;
    cv.h = h;
    return cv.u;
}

// log2(e)/64 : folds both the 1/hd score scale and the exp->exp2 conversion into Q
#define Q_PRESCALE 0.022542110f
// log2(1e8)/128
#define FREQ_L2 0.20762050593046f

// ---------------------------------------------------------------------------
// fp32 -> bf16 bulk convert: grid (nblk,1,3), 8 elements/thread.
// ---------------------------------------------------------------------------
__global__ __launch_bounds__(256) void conv3_bf16(
    const float* __restrict__ a, const float* __restrict__ b,
    const float* __restrict__ c, unsigned short* __restrict__ dst,
    int zstride)
{
    const int z = blockIdx.z;
    const float* src = (z == 0) ? a : ((z == 1) ? b : c);
    const size_t i = ((size_t)blockIdx.x * 256 + threadIdx.x) * 8;
    const float4* p = (const float4*)(src + i);
    float4 x0 = p[0], x1 = p[1];
    FragU f;
    f.u[0] = pack2_bf16(x0.x, x0.y);
    f.u[1] = pack2_bf16(x0.z, x0.w);
    f.u[2] = pack2_bf16(x1.x, x1.y);
    f.u[3] = pack2_bf16(x1.z, x1.w);
    *(s16x8*)(dst + (size_t)z * zstride + i) = f.v;
}

// ---------------------------------------------------------------------------
// Kernel 1 (new): C = Xbf @ Wbf^T + b, rotary, bf16 pack into (bh, s, d).
// grid (4, 64, 3), block 256. bf16 direct global loads, no converts in loop.
// ---------------------------------------------------------------------------
__global__ __launch_bounds__(256) void qkv_rope_bf16(
    const unsigned short* __restrict__ xbf, const unsigned short* __restrict__ wbf,
    const float* __restrict__ bq, const float* __restrict__ bk,
    const float* __restrict__ bv, unsigned short* __restrict__ dst_base)
{
    const int z = blockIdx.z;
    const unsigned short* X = xbf + (size_t)z * 4194304;
    const unsigned short* W = wbf + (size_t)z * 262144;
    const float* bias = (z == 0) ? bq : ((z == 1) ? bk : bv);
    unsigned short* dst = dst_base + (size_t)z * (size_t)(2 * NH * S_LEN * HDIM);

    const int tid  = threadIdx.x;
    const int wv   = tid >> 6;
    const int lane = tid & 63;
    const int c31  = lane & 31;
    const int hi   = lane >> 5;
    const int wm   = wv >> 1, wn = wv & 1;

    const int m0 = blockIdx.y * 128 + wm * 64;
    const int n0 = blockIdx.x * 128 + wn * 64;

    f32x16 acc[2][2];
    #pragma unroll
    for (int a = 0; a < 2; ++a)
    #pragma unroll
    for (int b = 0; b < 2; ++b)
    #pragma unroll
    for (int r = 0; r < 16; ++r) acc[a][b][r] = 0.f;

    const unsigned short* xp0 = X + (size_t)(m0 + c31) * 512 + hi * 8;
    const unsigned short* xp1 = X + (size_t)(m0 + 32 + c31) * 512 + hi * 8;
    const unsigned short* wp0 = W + (size_t)(n0 + c31) * 512 + hi * 8;
    const unsigned short* wp1 = W + (size_t)(n0 + 32 + c31) * 512 + hi * 8;

    #pragma unroll 2
    for (int kc = 0; kc < 32; ++kc) {
        const int kofs = kc * 16;
        s16x8 a0 = *(const s16x8*)(xp0 + kofs);
        s16x8 a1 = *(const s16x8*)(xp1 + kofs);
        s16x8 b0 = *(const s16x8*)(wp0 + kofs);
        s16x8 b1 = *(const s16x8*)(wp1 + kofs);
        acc[0][0] = __builtin_amdgcn_mfma_f32_32x32x16_bf16(a0, b0, acc[0][0], 0, 0, 0);
        acc[0][1] = __builtin_amdgcn_mfma_f32_32x32x16_bf16(a0, b1, acc[0][1], 0, 0, 0);
        acc[1][0] = __builtin_amdgcn_mfma_f32_32x32x16_bf16(a1, b0, acc[1][0], 0, 0, 0);
        acc[1][1] = __builtin_amdgcn_mfma_f32_32x32x16_bf16(a1, b1, acc[1][1], 0, 0, 0);
    }

    #pragma unroll
    for (int nt = 0; nt < 2; ++nt) {
        const int o = n0 + nt * 32 + c31;          // output channel
        const float bv_ = bias[o];
        float freq = 0.f;
        int sel = 0;
        if (z < 2) {
            freq = exp2f(-(float)(o >> 2) * FREQ_L2);
            sel  = (o >> 1) & 1;
        }
        #pragma unroll
        for (int mt = 0; mt < 2; ++mt) {
            #pragma unroll
            for (int r = 0; r < 16; ++r) {
                const int m = m0 + mt * 32 + (r & 3) + 8 * (r >> 2) + 4 * hi;
                const int s = m & 4095;
                float val = acc[mt][nt][r] + bv_;
                float res;
                if (z < 2) {
                    const float pos = (float)(sel ? (s & 63) : (s >> 6));
                    float sv, cv_;
                    __sincosf(pos * freq, &sv, &cv_);
                    const float partner = __shfl_xor(val, 1);
                    const float sg = (o & 1) ? sv : -sv;   // even: xr*c - xi*s ; odd: xr*s + xi*c
                    res = fmaf(partner, sg, val * cv_);
                    if (z == 0) res *= Q_PRESCALE;
                } else {
                    res = val;
                }
                const int b  = m >> 12;
                const int bh = b * NH + (o >> 6);
                dst[(size_t)bh * (S_LEN * HDIM) + (size_t)s * HDIM + (o & 63)] = to_bf16(res);
            }
        }
    }
}

// ---------------------------------------------------------------------------
// Kernel 1 (fallback, fp32 inputs) — proven r1 version, used if ws too small.
// ---------------------------------------------------------------------------
__global__ __launch_bounds__(256) void qkv_rope_proj(
    const float* __restrict__ q_in, const float* __restrict__ k_in,
    const float* __restrict__ v_in,
    const float* __restrict__ Wq, const float* __restrict__ bq,
    const float* __restrict__ Wk, const float* __restrict__ bk,
    const float* __restrict__ Wv, const float* __restrict__ bv,
    unsigned short* __restrict__ ws)
{
    const int z = blockIdx.z;
    const float* X    = (z == 0) ? q_in : ((z == 1) ? k_in : v_in);
    const float* W    = (z == 0) ? Wq   : ((z == 1) ? Wk   : Wv);
    const float* bias = (z == 0) ? bq   : ((z == 1) ? bk   : bv);
    unsigned short* dst = ws + (size_t)z * (size_t)(2 * NH * S_LEN * HDIM);

    const int tid  = threadIdx.x;
    const int wv   = tid >> 6;
    const int lane = tid & 63;
    const int c31  = lane & 31;
    const int hi   = lane >> 5;
    const int wm   = wv >> 1, wn = wv & 1;

    const int m0 = blockIdx.y * 128 + wm * 64;
    const int n0 = blockIdx.x * 128 + wn * 64;

    f32x16 acc[2][2];
    #pragma unroll
    for (int a = 0; a < 2; ++a)
    #pragma unroll
    for (int b = 0; b < 2; ++b)
    #pragma unroll
    for (int r = 0; r < 16; ++r) acc[a][b][r] = 0.f;

    for (int kc = 0; kc < 32; ++kc) {
        const int kofs = kc * 16 + hi * 8;
        FragU a_f[2], b_f[2];
        #pragma unroll
        for (int mt = 0; mt < 2; ++mt) {
            const float4* p = (const float4*)(X + (size_t)(m0 + mt * 32 + c31) * 512 + kofs);
            float4 x0 = p[0], x1 = p[1];
            a_f[mt].u[0] = pack2_bf16(x0.x, x0.y);
            a_f[mt].u[1] = pack2_bf16(x0.z, x0.w);
            a_f[mt].u[2] = pack2_bf16(x1.x, x1.y);
            a_f[mt].u[3] = pack2_bf16(x1.z, x1.w);
        }
        #pragma unroll
        for (int nt = 0; nt < 2; ++nt) {
            const float4* p = (const float4*)(W + (size_t)(n0 + nt * 32 + c31) * 512 + kofs);
            float4 x0 = p[0], x1 = p[1];
            b_f[nt].u[0] = pack2_bf16(x0.x, x0.y);
            b_f[nt].u[1] = pack2_bf16(x0.z, x0.w);
            b_f[nt].u[2] = pack2_bf16(x1.x, x1.y);
            b_f[nt].u[3] = pack2_bf16(x1.z, x1.w);
        }
        #pragma unroll
        for (int mt = 0; mt < 2; ++mt)
        #pragma unroll
        for (int nt = 0; nt < 2; ++nt)
            acc[mt][nt] = __builtin_amdgcn_mfma_f32_32x32x16_bf16(
                a_f[mt].v, b_f[nt].v, acc[mt][nt], 0, 0, 0);
    }

    #pragma unroll
    for (int nt = 0; nt < 2; ++nt) {
        const int o = n0 + nt * 32 + c31;
        const float bv_ = bias[o];
        float freq = 0.f;
        int sel = 0;
        if (z < 2) {
            freq = exp2f(-(float)(o >> 2) * FREQ_L2);
            sel  = (o >> 1) & 1;
        }
        #pragma unroll
        for (int mt = 0; mt < 2; ++mt) {
            #pragma unroll
            for (int r = 0; r < 16; ++r) {
                const int m = m0 + mt * 32 + (r & 3) + 8 * (r >> 2) + 4 * hi;
                const int s = m & 4095;
                float val = acc[mt][nt][r] + bv_;
                float res;
                if (z < 2) {
                    const float pos = (float)(sel ? (s & 63) : (s >> 6));
                    float sv, cv_;
                    __sincosf(pos * freq, &sv, &cv_);
                    const float partner = __shfl_xor(val, 1);
                    const float sg = (o & 1) ? sv : -sv;
                    res = fmaf(partner, sg, val * cv_);
                    if (z == 0) res *= Q_PRESCALE;
                } else {
                    res = val;
                }
                const int b  = m >> 12;
                const int bh = b * NH + (o >> 6);
                dst[(size_t)bh * (S_LEN * HDIM) + (size_t)s * HDIM + (o & 63)] = to_bf16(res);
            }
        }
    }
}

// ---------------------------------------------------------------------------
// Kernel 2: flash attention (S^T trick), software-pipelined:
//   - V row loads issued at iter top, consumed after S^T+exp (~400 cyc later)
//   - next iter's K A-frags prefetched across the exp/PV phase
//   - V^T LDS stride 36 ushorts (2-way banks on write b32 and read b128)
// grid (64, 16), block 256.
// ---------------------------------------------------------------------------
#define V_STRIDE 36

__global__ __launch_bounds__(256) void flash_attn_st(
    const unsigned short* __restrict__ qkv, float* __restrict__ out)
{
    __shared__ __align__(16) unsigned char smem[33792];
    unsigned short* sVt_all = (unsigned short*)smem;          // 4 waves * 64*36 ushorts
    float* sOb = (float*)smem;                                 // 2 * 4096 floats (post-loop)
    float* sL  = (float*)(smem + 32768);                       // 4*2*32 floats

    const int tid  = threadIdx.x;
    const int wv   = tid >> 6;
    const int lane = tid & 63;
    const int c31  = lane & 31;
    const int hi   = lane >> 5;
    const int q0   = blockIdx.x * 64;
    const int bh   = blockIdx.y;

    const unsigned short* Qb = qkv + (size_t)bh * (S_LEN * HDIM);
    const unsigned short* Kb = qkv + (size_t)4194304 + (size_t)bh * (S_LEN * HDIM);
    const unsigned short* Vb = qkv + (size_t)8388608 + (size_t)bh * (S_LEN * HDIM);

    unsigned short* sVt = sVt_all + wv * (64 * V_STRIDE);

    // Q B-frags: B[k][n] = Q[q0+qt*32+n][kc*16 + k], n=c31, k=hi*8+j
    s16x8 qf[2][4];
    #pragma unroll
    for (int qt = 0; qt < 2; ++qt)
    #pragma unroll
    for (int kc = 0; kc < 4; ++kc)
        qf[qt][kc] = *(const s16x8*)(Qb + (size_t)(q0 + qt * 32 + c31) * HDIM + kc * 16 + hi * 8);

    f32x16 o_acc[2][2];                   // [d-tile][q-tile], O^T layout
    #pragma unroll
    for (int a = 0; a < 2; ++a)
    #pragma unroll
    for (int b = 0; b < 2; ++b)
    #pragma unroll
    for (int r = 0; r < 16; ++r) o_acc[a][b][r] = 0.f;
    float l_acc[2] = {0.f, 0.f};

    const int vs0 = (lane & 15) * 2;      // kv pair base for V staging
    const int vd0 = (lane >> 4) * 8;      // d octet base

    // preload K A-frags for iter 0
    s16x8 ka[4];
    {
        const int kv0 = wv * 32;
        #pragma unroll
        for (int kc = 0; kc < 4; ++kc)
            ka[kc] = *(const s16x8*)(Kb + (size_t)(kv0 + c31) * HDIM + kc * 16 + hi * 8);
    }

    for (int it = 0; it < 32; ++it) {
        const int kv0 = (it * 4 + wv) * 32;
        const int kvn = (it < 31) ? (kv0 + 128) : kv0;   // next-iter prefetch target

        // ---- issue V row loads now; consumed after S^T + exp ----
        FragU v0[2], v1[2];
        #pragma unroll
        for (int pass = 0; pass < 2; ++pass) {
            const unsigned short* vg = Vb + (size_t)(kv0 + vs0) * HDIM + vd0 + pass * 32;
            v0[pass].v = *(const s16x8*)vg;
            v1[pass].v = *(const s16x8*)(vg + HDIM);
        }

        // ---- qt0: S^T = K * Q^T, exp2, pack ----
        unsigned int up[2][8];
        {
            f32x16 st;
            #pragma unroll
            for (int r = 0; r < 16; ++r) st[r] = 0.f;
            #pragma unroll
            for (int kc = 0; kc < 4; ++kc)
                st = __builtin_amdgcn_mfma_f32_32x32x16_bf16(ka[kc], qf[0][kc], st, 0, 0, 0);
            float2 ls = {0.f, 0.f};
            #pragma unroll
            for (int qq = 0; qq < 8; ++qq) {
                float p0 = exp2f(st[2 * qq]);
                float p1 = exp2f(st[2 * qq + 1]);
                ls.x += p0; ls.y += p1;
                up[0][qq] = pack2_bf16(p0, p1);
            }
            l_acc[0] += ls.x + ls.y;
        }

        // ---- prefetch next iter's K A-frags (latency hidden by qt1 + PV) ----
        s16x8 kan[4];
        #pragma unroll
        for (int kc = 0; kc < 4; ++kc)
            kan[kc] = *(const s16x8*)(Kb + (size_t)(kvn + c31) * HDIM + kc * 16 + hi * 8);

        // ---- qt1: S^T, exp2, pack ----
        {
            f32x16 st;
            #pragma unroll
            for (int r = 0; r < 16; ++r) st[r] = 0.f;
            #pragma unroll
            for (int kc = 0; kc < 4; ++kc)
                st = __builtin_amdgcn_mfma_f32_32x32x16_bf16(ka[kc], qf[1][kc], st, 0, 0, 0);
            float2 ls = {0.f, 0.f};
            #pragma unroll
            for (int qq = 0; qq < 8; ++qq) {
                float p0 = exp2f(st[2 * qq]);
                float p1 = exp2f(st[2 * qq + 1]);
                ls.x += p0; ls.y += p1;
                up[1][qq] = pack2_bf16(p0, p1);
            }
            l_acc[1] += ls.x + ls.y;
        }

        // ---- stage V^T into LDS (Vt[d][kv], stride 36) ----
        #pragma unroll
        for (int pass = 0; pass < 2; ++pass) {
            const int d0 = vd0 + pass * 32;
            #pragma unroll
            for (int j = 0; j < 8; ++j) {
                unsigned int pk = (unsigned int)v0[pass].h[j] | ((unsigned int)v1[pass].h[j] << 16);
                *(unsigned int*)(sVt + (d0 + j) * V_STRIDE + vs0) = pk;
            }
        }

        // ---- V^T A-frags from LDS ----
        s16x8 va[2][2];
        #pragma unroll
        for (int dt = 0; dt < 2; ++dt)
        #pragma unroll
        for (int k2 = 0; k2 < 2; ++k2)
            va[dt][k2] = *(const s16x8*)(sVt + (dt * 32 + c31) * V_STRIDE + k2 * 16 + hi * 8);

        // ---- O^T += V^T * P^T ; P^T B-frag assembled via shfl_xor(32) ----
        #pragma unroll
        for (int qt = 0; qt < 2; ++qt) {
            #pragma unroll
            for (int k2 = 0; k2 < 2; ++k2) {
                const unsigned int a0 = up[qt][4 * k2 + 0];
                const unsigned int a1 = up[qt][4 * k2 + 1];
                const unsigned int a2 = up[qt][4 * k2 + 2];
                const unsigned int a3 = up[qt][4 * k2 + 3];
                const unsigned int s0 = (unsigned int)__shfl_xor((int)(hi ? a0 : a2), 32);
                const unsigned int s1 = (unsigned int)__shfl_xor((int)(hi ? a1 : a3), 32);
                FragU pb;
                pb.u[0] = hi ? s0 : a0;
                pb.u[1] = hi ? s1 : a1;
                pb.u[2] = hi ? a2 : s0;
                pb.u[3] = hi ? a3 : s1;
                #pragma unroll
                for (int dt = 0; dt < 2; ++dt)
                    o_acc[dt][qt] = __builtin_amdgcn_mfma_f32_32x32x16_bf16(
                        va[dt][k2], pb.v, o_acc[dt][qt], 0, 0, 0);
            }
        }

        #pragma unroll
        for (int kc = 0; kc < 4; ++kc) ka[kc] = kan[kc];
    }

    // ---- merge partials across the 4 waves ----
    {
        float l0 = l_acc[0] + __shfl_xor(l_acc[0], 32);
        float l1 = l_acc[1] + __shfl_xor(l_acc[1], 32);
        if (lane < 32) {
            sL[(wv * 2 + 0) * 32 + lane] = l0;
            sL[(wv * 2 + 1) * 32 + lane] = l1;
        }
    }
    __syncthreads();

    if (wv == 1 || wv == 2) {
        float* buf = sOb + (wv - 1) * 4096;
        #pragma unroll
        for (int dt = 0; dt < 2; ++dt)
        #pragma unroll
        for (int qt = 0; qt < 2; ++qt)
        #pragma unroll
        for (int r = 0; r < 16; ++r) {
            const int d = dt * 32 + (r & 3) + 8 * (r >> 2) + 4 * hi;
            buf[d * 64 + qt * 32 + c31] = o_acc[dt][qt][r];
        }
    }
    __syncthreads();
    if (wv == 0 || wv == 3) {
        const float* buf = sOb + ((wv == 0) ? 0 : 4096);
        #pragma unroll
        for (int dt = 0; dt < 2; ++dt)
        #pragma unroll
        for (int qt = 0; qt < 2; ++qt)
        #pragma unroll
        for (int r = 0; r < 16; ++r) {
            const int d = dt * 32 + (r & 3) + 8 * (r >> 2) + 4 * hi;
            o_acc[dt][qt][r] += buf[d * 64 + qt * 32 + c31];
        }
    }
    __syncthreads();
    if (wv == 3) {
        #pragma unroll
        for (int dt = 0; dt < 2; ++dt)
        #pragma unroll
        for (int qt = 0; qt < 2; ++qt)
        #pragma unroll
        for (int r = 0; r < 16; ++r) {
            const int d = dt * 32 + (r & 3) + 8 * (r >> 2) + 4 * hi;
            sOb[d * 64 + qt * 32 + c31] = o_acc[dt][qt][r];
        }
    }
    __syncthreads();
    if (wv == 0) {
        #pragma unroll
        for (int dt = 0; dt < 2; ++dt)
        #pragma unroll
        for (int qt = 0; qt < 2; ++qt)
        #pragma unroll
        for (int r = 0; r < 16; ++r) {
            const int d = dt * 32 + (r & 3) + 8 * (r >> 2) + 4 * hi;
            o_acc[dt][qt][r] += sOb[d * 64 + qt * 32 + c31];
        }
        const int b  = bh >> 3;
        const int hh = bh & 7;
        #pragma unroll
        for (int qt = 0; qt < 2; ++qt) {
            const float lsum = sL[(0 * 2 + qt) * 32 + c31] + sL[(1 * 2 + qt) * 32 + c31]
                             + sL[(2 * 2 + qt) * 32 + c31] + sL[(3 * 2 + qt) * 32 + c31];
            const float rinv = 1.f / lsum;
            const int s = q0 + qt * 32 + c31;
            float* orow = out + ((size_t)b * S_LEN + s) * 512 + hh * 64;
            #pragma unroll
            for (int dt = 0; dt < 2; ++dt) {
                #pragma unroll
                for (int g = 0; g < 4; ++g) {
                    float4 vv;
                    vv.x = o_acc[dt][qt][4 * g + 0] * rinv;
                    vv.y = o_acc[dt][qt][4 * g + 1] * rinv;
                    vv.z = o_acc[dt][qt][4 * g + 2] * rinv;
                    vv.w = o_acc[dt][qt][4 * g + 3] * rinv;
                    *(float4*)(orow + dt * 32 + 8 * g + 4 * hi) = vv;
                }
            }
        }
    }
}

extern "C" void kernel_launch(void* const* d_in, const int* in_sizes, int n_in,
                              void* d_out, int out_size, void* d_ws, size_t ws_size,
                              hipStream_t stream) {
    (void)in_sizes; (void)n_in; (void)out_size;
    const float* q_in = (const float*)d_in[0];
    const float* k_in = (const float*)d_in[1];
    const float* v_in = (const float*)d_in[2];
    const float* Wq   = (const float*)d_in[3];
    const float* bq   = (const float*)d_in[4];
    const float* Wk   = (const float*)d_in[5];
    const float* bk   = (const float*)d_in[6];
    const float* Wv   = (const float*)d_in[7];
    const float* bv   = (const float*)d_in[8];
    unsigned short* ws = (unsigned short*)d_ws;
    float* out = (float*)d_out;

    if (ws_size >= WS_NEED_BYTES) {
        conv3_bf16<<<dim3(2048, 1, 3), 256, 0, stream>>>(q_in, k_in, v_in, ws + XBF_OFF, 4194304);
        conv3_bf16<<<dim3(128, 1, 3), 256, 0, stream>>>(Wq, Wk, Wv, ws + WBF_OFF, 262144);
        qkv_rope_bf16<<<dim3(4, 64, 3), 256, 0, stream>>>(
            ws + XBF_OFF, ws + WBF_OFF, bq, bk, bv, ws + QKV_OFF);
        flash_attn_st<<<dim3(64, 16), 256, 0, stream>>>(ws + QKV_OFF, out);
    } else {
        qkv_rope_proj<<<dim3(4, 64, 3), 256, 0, stream>>>(
            q_in, k_in, v_in, Wq, bq, Wk, bk, Wv, bv, ws);
        flash_attn_st<<<dim3(64, 16), 256, 0, stream>>>(ws, out);
    }
}

// Round 3
// 302.221 us; speedup vs baseline: 1.2020x; 1.0449x over previous
//
#include <hip/hip_runtime.h>
#include <hip/hip_bf16.h>

#define S_LEN 4096
#define HDIM  64
#define NH    8

// Vt row stride (elements): 4096 + 16 pad — breaks 8KB power-of-2 L2 set aliasing,
// keeps 16B alignment for per-lane x8 bf16 loads.
#define VT_STR 4112

// ws layout (ushort units) for the big-ws path
#define XBF_OFF   0            // 3 * 4194304  (bf16 X for q,k,v inputs)
#define WBF_OFF   12582912     // 3 * 262144   (bf16 W)
#define QKV_OFF   13369344     // Q(4194304) + K(4194304) + Vt(16*64*4112 = 4210688)
#define QKV_BYTES ((size_t)(4194304 + 4194304 + 4210688) * 2)
#define WS_NEED_BYTES ((size_t)(13369344 + 4194304 + 4194304 + 4210688) * 2)   // 51937280
#define FB_NEED_BYTES QKV_BYTES                                                // 25187... fallback

typedef short s16x8 __attribute__((ext_vector_type(8)));
typedef float f32x16 __attribute__((ext_vector_type(16)));
typedef unsigned short u16x4 __attribute__((ext_vector_type(4)));

union FragU {
    s16x8 v;
    unsigned int u[4];
    unsigned short h[8];
};

static __device__ __forceinline__ unsigned int pack2_bf16(float a, float b) {
    __hip_bfloat162 h2 = __float22bfloat162_rn(float2{a, b});
    union { __hip_bfloat162 h; unsigned int u; } cv;
    cv.h = h2;
    return cv.u;
}

static __device__ __forceinline__ unsigned short to_bf16(float a) {
    __hip_bfloat16 h = __float2bfloat16(a);
    union { __hip_bfloat16 h; unsigned short u; } cv;
    cv.h = h;
    return cv.u;
}

// log2(e)/64 : folds both the 1/hd score scale and the exp->exp2 conversion into Q
#define Q_PRESCALE 0.022542110f
// log2(1e8)/128
#define FREQ_L2 0.20762050593046f

// ---------------------------------------------------------------------------
// fp32 -> bf16 bulk convert: grid (nblk,1,3), 8 elements/thread.
// ---------------------------------------------------------------------------
__global__ __launch_bounds__(256) void conv3_bf16(
    const float* __restrict__ a, const float* __restrict__ b,
    const float* __restrict__ c, unsigned short* __restrict__ dst,
    int zstride)
{
    const int z = blockIdx.z;
    const float* src = (z == 0) ? a : ((z == 1) ? b : c);
    const size_t i = ((size_t)blockIdx.x * 256 + threadIdx.x) * 8;
    const float4* p = (const float4*)(src + i);
    float4 x0 = p[0], x1 = p[1];
    FragU f;
    f.u[0] = pack2_bf16(x0.x, x0.y);
    f.u[1] = pack2_bf16(x0.z, x0.w);
    f.u[2] = pack2_bf16(x1.x, x1.y);
    f.u[3] = pack2_bf16(x1.z, x1.w);
    *(s16x8*)(dst + (size_t)z * zstride + i) = f.v;
}

// ---------------------------------------------------------------------------
// Shared epilogue: bias (+rotary+prescale for Q/K), bf16 pack.
// z<2 : dst_base + z*4194304, layout (bh, s, d)
// z==2: dst_base + 8388608,  layout (bh, d, s) row stride VT_STR  (V transposed)
// ---------------------------------------------------------------------------
static __device__ __forceinline__ void qkv_epilogue(
    int z, const f32x16 acc[2][2], int m0, int n0, int c31, int hi,
    const float* __restrict__ bias, unsigned short* __restrict__ dst_base)
{
    if (z < 2) {
        unsigned short* dst = dst_base + (size_t)z * 4194304;
        #pragma unroll
        for (int nt = 0; nt < 2; ++nt) {
            const int o = n0 + nt * 32 + c31;
            const float bv_ = bias[o];
            const float freq = exp2f(-(float)(o >> 2) * FREQ_L2);
            const int sel = (o >> 1) & 1;
            #pragma unroll
            for (int mt = 0; mt < 2; ++mt) {
                #pragma unroll
                for (int r = 0; r < 16; ++r) {
                    const int m = m0 + mt * 32 + (r & 3) + 8 * (r >> 2) + 4 * hi;
                    const int s = m & 4095;
                    float val = acc[mt][nt][r] + bv_;
                    const float pos = (float)(sel ? (s & 63) : (s >> 6));
                    float sv, cv_;
                    __sincosf(pos * freq, &sv, &cv_);
                    const float partner = __shfl_xor(val, 1);
                    const float sg = (o & 1) ? sv : -sv;   // even: xr*c - xi*s ; odd: xr*s + xi*c
                    float res = fmaf(partner, sg, val * cv_);
                    if (z == 0) res *= Q_PRESCALE;
                    const int b  = m >> 12;
                    const int bh = b * NH + (o >> 6);
                    dst[(size_t)bh * (S_LEN * HDIM) + (size_t)s * HDIM + (o & 63)] = to_bf16(res);
                }
            }
        }
    } else {
        unsigned short* vt = dst_base + 8388608;
        #pragma unroll
        for (int nt = 0; nt < 2; ++nt) {
            const int o = n0 + nt * 32 + c31;
            const float bv_ = bias[o];
            const int d = o & 63, hh = o >> 6;
            #pragma unroll
            for (int mt = 0; mt < 2; ++mt) {
                #pragma unroll
                for (int g = 0; g < 4; ++g) {
                    const int mbase = m0 + mt * 32 + 8 * g + 4 * hi;  // 4-aligned run of s
                    const int s = mbase & 4095;
                    const int b = mbase >> 12;
                    u16x4 pk;
                    pk.x = to_bf16(acc[mt][nt][4 * g + 0] + bv_);
                    pk.y = to_bf16(acc[mt][nt][4 * g + 1] + bv_);
                    pk.z = to_bf16(acc[mt][nt][4 * g + 2] + bv_);
                    pk.w = to_bf16(acc[mt][nt][4 * g + 3] + bv_);
                    *(u16x4*)(vt + ((size_t)((b * NH + hh) * 64 + d)) * VT_STR + s) = pk;
                }
            }
        }
    }
}

// ---------------------------------------------------------------------------
// Kernel 1: C = Xbf @ Wbf^T + b, rotary, bf16 pack. bf16 direct global loads.
// grid (4, 64, 3), block 256.
// ---------------------------------------------------------------------------
__global__ __launch_bounds__(256) void qkv_rope_bf16(
    const unsigned short* __restrict__ xbf, const unsigned short* __restrict__ wbf,
    const float* __restrict__ bq, const float* __restrict__ bk,
    const float* __restrict__ bv, unsigned short* __restrict__ dst_base)
{
    const int z = blockIdx.z;
    const unsigned short* X = xbf + (size_t)z * 4194304;
    const unsigned short* W = wbf + (size_t)z * 262144;
    const float* bias = (z == 0) ? bq : ((z == 1) ? bk : bv);

    const int tid  = threadIdx.x;
    const int wv   = tid >> 6;
    const int lane = tid & 63;
    const int c31  = lane & 31;
    const int hi   = lane >> 5;
    const int wm   = wv >> 1, wn = wv & 1;

    const int m0 = blockIdx.y * 128 + wm * 64;
    const int n0 = blockIdx.x * 128 + wn * 64;

    f32x16 acc[2][2];
    #pragma unroll
    for (int a = 0; a < 2; ++a)
    #pragma unroll
    for (int b = 0; b < 2; ++b)
    #pragma unroll
    for (int r = 0; r < 16; ++r) acc[a][b][r] = 0.f;

    const unsigned short* xp0 = X + (size_t)(m0 + c31) * 512 + hi * 8;
    const unsigned short* xp1 = X + (size_t)(m0 + 32 + c31) * 512 + hi * 8;
    const unsigned short* wp0 = W + (size_t)(n0 + c31) * 512 + hi * 8;
    const unsigned short* wp1 = W + (size_t)(n0 + 32 + c31) * 512 + hi * 8;

    #pragma unroll 2
    for (int kc = 0; kc < 32; ++kc) {
        const int kofs = kc * 16;
        s16x8 a0 = *(const s16x8*)(xp0 + kofs);
        s16x8 a1 = *(const s16x8*)(xp1 + kofs);
        s16x8 b0 = *(const s16x8*)(wp0 + kofs);
        s16x8 b1 = *(const s16x8*)(wp1 + kofs);
        acc[0][0] = __builtin_amdgcn_mfma_f32_32x32x16_bf16(a0, b0, acc[0][0], 0, 0, 0);
        acc[0][1] = __builtin_amdgcn_mfma_f32_32x32x16_bf16(a0, b1, acc[0][1], 0, 0, 0);
        acc[1][0] = __builtin_amdgcn_mfma_f32_32x32x16_bf16(a1, b0, acc[1][0], 0, 0, 0);
        acc[1][1] = __builtin_amdgcn_mfma_f32_32x32x16_bf16(a1, b1, acc[1][1], 0, 0, 0);
    }

    qkv_epilogue(z, acc, m0, n0, c31, hi, bias, dst_base);
}

// ---------------------------------------------------------------------------
// Kernel 1 (fallback, fp32 inputs) — used if ws too small for bf16 pre-pass.
// ---------------------------------------------------------------------------
__global__ __launch_bounds__(256) void qkv_rope_proj(
    const float* __restrict__ q_in, const float* __restrict__ k_in,
    const float* __restrict__ v_in,
    const float* __restrict__ Wq, const float* __restrict__ bq,
    const float* __restrict__ Wk, const float* __restrict__ bk,
    const float* __restrict__ Wv, const float* __restrict__ bv,
    unsigned short* __restrict__ dst_base)
{
    const int z = blockIdx.z;
    const float* X    = (z == 0) ? q_in : ((z == 1) ? k_in : v_in);
    const float* W    = (z == 0) ? Wq   : ((z == 1) ? Wk   : Wv);
    const float* bias = (z == 0) ? bq   : ((z == 1) ? bk   : bv);

    const int tid  = threadIdx.x;
    const int wv   = tid >> 6;
    const int lane = tid & 63;
    const int c31  = lane & 31;
    const int hi   = lane >> 5;
    const int wm   = wv >> 1, wn = wv & 1;

    const int m0 = blockIdx.y * 128 + wm * 64;
    const int n0 = blockIdx.x * 128 + wn * 64;

    f32x16 acc[2][2];
    #pragma unroll
    for (int a = 0; a < 2; ++a)
    #pragma unroll
    for (int b = 0; b < 2; ++b)
    #pragma unroll
    for (int r = 0; r < 16; ++r) acc[a][b][r] = 0.f;

    for (int kc = 0; kc < 32; ++kc) {
        const int kofs = kc * 16 + hi * 8;
        FragU a_f[2], b_f[2];
        #pragma unroll
        for (int mt = 0; mt < 2; ++mt) {
            const float4* p = (const float4*)(X + (size_t)(m0 + mt * 32 + c31) * 512 + kofs);
            float4 x0 = p[0], x1 = p[1];
            a_f[mt].u[0] = pack2_bf16(x0.x, x0.y);
            a_f[mt].u[1] = pack2_bf16(x0.z, x0.w);
            a_f[mt].u[2] = pack2_bf16(x1.x, x1.y);
            a_f[mt].u[3] = pack2_bf16(x1.z, x1.w);
        }
        #pragma unroll
        for (int nt = 0; nt < 2; ++nt) {
            const float4* p = (const float4*)(W + (size_t)(n0 + nt * 32 + c31) * 512 + kofs);
            float4 x0 = p[0], x1 = p[1];
            b_f[nt].u[0] = pack2_bf16(x0.x, x0.y);
            b_f[nt].u[1] = pack2_bf16(x0.z, x0.w);
            b_f[nt].u[2] = pack2_bf16(x1.x, x1.y);
            b_f[nt].u[3] = pack2_bf16(x1.z, x1.w);
        }
        #pragma unroll
        for (int mt = 0; mt < 2; ++mt)
        #pragma unroll
        for (int nt = 0; nt < 2; ++nt)
            acc[mt][nt] = __builtin_amdgcn_mfma_f32_32x32x16_bf16(
                a_f[mt].v, b_f[nt].v, acc[mt][nt], 0, 0, 0);
    }

    qkv_epilogue(z, acc, m0, n0, c31, hi, bias, dst_base);
}

// ---------------------------------------------------------------------------
// Kernel 2: flash attention (S^T trick).
//  - No LDS / no barriers in main loop (waves own disjoint KV tiles)
//  - V^T A-frags loaded DIRECTLY from global (pre-transposed Vt), issued at
//    iter top, consumed ~450 cyc later
//  - K A-frags prefetched into the SAME registers right after last use
//  - raw v_exp_f32 via __builtin_amdgcn_exp2f
//  - __launch_bounds__(256,3): cap regs for 3 waves/SIMD
// grid (64, 16), block 256.
// ---------------------------------------------------------------------------
__global__ __launch_bounds__(256, 3) void flash_attn_st(
    const unsigned short* __restrict__ qkv, float* __restrict__ out)
{
    __shared__ __align__(16) unsigned char smem[33792];
    float* sOb = (float*)smem;                                 // 2 * 4096 floats (post-loop)
    float* sL  = (float*)(smem + 32768);                       // 4*2*32 floats

    const int tid  = threadIdx.x;
    const int wv   = tid >> 6;
    const int lane = tid & 63;
    const int c31  = lane & 31;
    const int hi   = lane >> 5;
    const int q0   = blockIdx.x * 64;
    const int bh   = blockIdx.y;

    const unsigned short* Qb  = qkv + (size_t)bh * (S_LEN * HDIM);
    const unsigned short* Kb  = qkv + (size_t)4194304 + (size_t)bh * (S_LEN * HDIM);
    const unsigned short* Vtb = qkv + (size_t)8388608 + (size_t)bh * (64 * VT_STR);

    // Q B-frags: B[k][n] = Q[q0+qt*32+n][kc*16 + k], n=c31, k=hi*8+j
    s16x8 qf[2][4];
    #pragma unroll
    for (int qt = 0; qt < 2; ++qt)
    #pragma unroll
    for (int kc = 0; kc < 4; ++kc)
        qf[qt][kc] = *(const s16x8*)(Qb + (size_t)(q0 + qt * 32 + c31) * HDIM + kc * 16 + hi * 8);

    f32x16 o_acc[2][2];                   // [d-tile][q-tile], O^T layout
    #pragma unroll
    for (int a = 0; a < 2; ++a)
    #pragma unroll
    for (int b = 0; b < 2; ++b)
    #pragma unroll
    for (int r = 0; r < 16; ++r) o_acc[a][b][r] = 0.f;
    float l_acc[2] = {0.f, 0.f};

    // loop-invariant per-lane bases
    const unsigned short* kp  = Kb  + (size_t)(wv * 32 + c31) * HDIM + hi * 8;  // += 128*HDIM per iter
    const unsigned short* vp0 = Vtb + (size_t)c31        * VT_STR + wv * 32 + hi * 8;  // += 128/iter
    const unsigned short* vp1 = Vtb + (size_t)(32 + c31) * VT_STR + wv * 32 + hi * 8;

    // preload K A-frags for iter 0: A[m][k] = K[kv0+m][kc*16+k]
    s16x8 ka[4];
    #pragma unroll
    for (int kc = 0; kc < 4; ++kc)
        ka[kc] = *(const s16x8*)(kp + kc * 16);

    for (int it = 0; it < 32; ++it) {
        // ---- issue V^T A-frag loads now; consumed at iter end ----
        s16x8 va[2][2];
        va[0][0] = *(const s16x8*)(vp0);
        va[0][1] = *(const s16x8*)(vp0 + 16);
        va[1][0] = *(const s16x8*)(vp1);
        va[1][1] = *(const s16x8*)(vp1 + 16);
        vp0 += 128; vp1 += 128;

        unsigned int up[2][8];

        // ---- qt0: S^T = K * Q^T, exp2, pack ----
        {
            f32x16 st;
            #pragma unroll
            for (int r = 0; r < 16; ++r) st[r] = 0.f;
            #pragma unroll
            for (int kc = 0; kc < 4; ++kc)
                st = __builtin_amdgcn_mfma_f32_32x32x16_bf16(ka[kc], qf[0][kc], st, 0, 0, 0);
            float ls0 = 0.f, ls1 = 0.f;
            #pragma unroll
            for (int qq = 0; qq < 8; ++qq) {
                float p0 = __builtin_amdgcn_exp2f(st[2 * qq]);
                float p1 = __builtin_amdgcn_exp2f(st[2 * qq + 1]);
                ls0 += p0; ls1 += p1;
                up[0][qq] = pack2_bf16(p0, p1);
            }
            l_acc[0] += ls0 + ls1;
        }

        // ---- qt1: S^T MFMAs (last use of ka) ----
        f32x16 st;
        #pragma unroll
        for (int r = 0; r < 16; ++r) st[r] = 0.f;
        #pragma unroll
        for (int kc = 0; kc < 4; ++kc)
            st = __builtin_amdgcn_mfma_f32_32x32x16_bf16(ka[kc], qf[1][kc], st, 0, 0, 0);

        // ---- prefetch next iter's K into the SAME ka regs (no extra VGPRs) ----
        kp += 128 * HDIM;
        if (it < 31) {
            #pragma unroll
            for (int kc = 0; kc < 4; ++kc)
                ka[kc] = *(const s16x8*)(kp + kc * 16);
        }

        // ---- qt1 exp2 + pack ----
        {
            float ls0 = 0.f, ls1 = 0.f;
            #pragma unroll
            for (int qq = 0; qq < 8; ++qq) {
                float p0 = __builtin_amdgcn_exp2f(st[2 * qq]);
                float p1 = __builtin_amdgcn_exp2f(st[2 * qq + 1]);
                ls0 += p0; ls1 += p1;
                up[1][qq] = pack2_bf16(p0, p1);
            }
            l_acc[1] += ls0 + ls1;
        }

        // ---- O^T += V^T * P^T ; P^T B-frag assembled via shfl_xor(32) ----
        #pragma unroll
        for (int qt = 0; qt < 2; ++qt) {
            #pragma unroll
            for (int k2 = 0; k2 < 2; ++k2) {
                const unsigned int a0 = up[qt][4 * k2 + 0];
                const unsigned int a1 = up[qt][4 * k2 + 1];
                const unsigned int a2 = up[qt][4 * k2 + 2];
                const unsigned int a3 = up[qt][4 * k2 + 3];
                const unsigned int s0 = (unsigned int)__shfl_xor((int)(hi ? a0 : a2), 32);
                const unsigned int s1 = (unsigned int)__shfl_xor((int)(hi ? a1 : a3), 32);
                FragU pb;
                pb.u[0] = hi ? s0 : a0;
                pb.u[1] = hi ? s1 : a1;
                pb.u[2] = hi ? a2 : s0;
                pb.u[3] = hi ? a3 : s1;
                #pragma unroll
                for (int dt = 0; dt < 2; ++dt)
                    o_acc[dt][qt] = __builtin_amdgcn_mfma_f32_32x32x16_bf16(
                        va[dt][k2], pb.v, o_acc[dt][qt], 0, 0, 0);
            }
        }
    }

    // ---- merge partials across the 4 waves ----
    {
        float l0 = l_acc[0] + __shfl_xor(l_acc[0], 32);
        float l1 = l_acc[1] + __shfl_xor(l_acc[1], 32);
        if (lane < 32) {
            sL[(wv * 2 + 0) * 32 + lane] = l0;
            sL[(wv * 2 + 1) * 32 + lane] = l1;
        }
    }
    __syncthreads();

    if (wv == 1 || wv == 2) {
        float* buf = sOb + (wv - 1) * 4096;
        #pragma unroll
        for (int dt = 0; dt < 2; ++dt)
        #pragma unroll
        for (int qt = 0; qt < 2; ++qt)
        #pragma unroll
        for (int r = 0; r < 16; ++r) {
            const int d = dt * 32 + (r & 3) + 8 * (r >> 2) + 4 * hi;
            buf[d * 64 + qt * 32 + c31] = o_acc[dt][qt][r];
        }
    }
    __syncthreads();
    if (wv == 0 || wv == 3) {
        const float* buf = sOb + ((wv == 0) ? 0 : 4096);
        #pragma unroll
        for (int dt = 0; dt < 2; ++dt)
        #pragma unroll
        for (int qt = 0; qt < 2; ++qt)
        #pragma unroll
        for (int r = 0; r < 16; ++r) {
            const int d = dt * 32 + (r & 3) + 8 * (r >> 2) + 4 * hi;
            o_acc[dt][qt][r] += buf[d * 64 + qt * 32 + c31];
        }
    }
    __syncthreads();
    if (wv == 3) {
        #pragma unroll
        for (int dt = 0; dt < 2; ++dt)
        #pragma unroll
        for (int qt = 0; qt < 2; ++qt)
        #pragma unroll
        for (int r = 0; r < 16; ++r) {
            const int d = dt * 32 + (r & 3) + 8 * (r >> 2) + 4 * hi;
            sOb[d * 64 + qt * 32 + c31] = o_acc[dt][qt][r];
        }
    }
    __syncthreads();
    if (wv == 0) {
        #pragma unroll
        for (int dt = 0; dt < 2; ++dt)
        #pragma unroll
        for (int qt = 0; qt < 2; ++qt)
        #pragma unroll
        for (int r = 0; r < 16; ++r) {
            const int d = dt * 32 + (r & 3) + 8 * (r >> 2) + 4 * hi;
            o_acc[dt][qt][r] += sOb[d * 64 + qt * 32 + c31];
        }
        const int b  = bh >> 3;
        const int hh = bh & 7;
        #pragma unroll
        for (int qt = 0; qt < 2; ++qt) {
            const float lsum = sL[(0 * 2 + qt) * 32 + c31] + sL[(1 * 2 + qt) * 32 + c31]
                             + sL[(2 * 2 + qt) * 32 + c31] + sL[(3 * 2 + qt) * 32 + c31];
            const float rinv = 1.f / lsum;
            const int s = q0 + qt * 32 + c31;
            float* orow = out + ((size_t)b * S_LEN + s) * 512 + hh * 64;
            #pragma unroll
            for (int dt = 0; dt < 2; ++dt) {
                #pragma unroll
                for (int g = 0; g < 4; ++g) {
                    float4 vv;
                    vv.x = o_acc[dt][qt][4 * g + 0] * rinv;
                    vv.y = o_acc[dt][qt][4 * g + 1] * rinv;
                    vv.z = o_acc[dt][qt][4 * g + 2] * rinv;
                    vv.w = o_acc[dt][qt][4 * g + 3] * rinv;
                    *(float4*)(orow + dt * 32 + 8 * g + 4 * hi) = vv;
                }
            }
        }
    }
}

extern "C" void kernel_launch(void* const* d_in, const int* in_sizes, int n_in,
                              void* d_out, int out_size, void* d_ws, size_t ws_size,
                              hipStream_t stream) {
    (void)in_sizes; (void)n_in; (void)out_size;
    const float* q_in = (const float*)d_in[0];
    const float* k_in = (const float*)d_in[1];
    const float* v_in = (const float*)d_in[2];
    const float* Wq   = (const float*)d_in[3];
    const float* bq   = (const float*)d_in[4];
    const float* Wk   = (const float*)d_in[5];
    const float* bk   = (const float*)d_in[6];
    const float* Wv   = (const float*)d_in[7];
    const float* bv   = (const float*)d_in[8];
    unsigned short* ws = (unsigned short*)d_ws;
    float* out = (float*)d_out;

    if (ws_size >= WS_NEED_BYTES) {
        conv3_bf16<<<dim3(2048, 1, 3), 256, 0, stream>>>(q_in, k_in, v_in, ws + XBF_OFF, 4194304);
        conv3_bf16<<<dim3(128, 1, 3), 256, 0, stream>>>(Wq, Wk, Wv, ws + WBF_OFF, 262144);
        qkv_rope_bf16<<<dim3(4, 64, 3), 256, 0, stream>>>(
            ws + XBF_OFF, ws + WBF_OFF, bq, bk, bv, ws + QKV_OFF);
        flash_attn_st<<<dim3(64, 16), 256, 0, stream>>>(ws + QKV_OFF, out);
    } else {
        qkv_rope_proj<<<dim3(4, 64, 3), 256, 0, stream>>>(
            q_in, k_in, v_in, Wq, bq, Wk, bk, Wv, bv, ws);
        flash_attn_st<<<dim3(64, 16), 256, 0, stream>>>(ws, out);
    }
}

// Round 4
// 236.913 us; speedup vs baseline: 1.5333x; 1.2757x over previous
//
#include <hip/hip_runtime.h>
#include <hip/hip_bf16.h>

#define S_LEN 4096
#define HDIM  64
#define NH    8

// ws layout (ushort element offsets), big-ws path:
//   XFRAG: 3 * 4194304   bf16 X (q,k,v inputs) in frag-tile layout
//   WFRAG: 3 * 262144    bf16 W in frag-tile layout
//   QKV:   Q(4194304) K(4194304) Vt(4194304), per-bh 262144, frag-tile layouts
#define XFRAG_OFF 0
#define WFRAG_OFF 12582912
#define QKV_OFF   13369344
#define WS_NEED_BYTES ((size_t)(13369344 + 12582912) * 2)      // 51,904,512
#define FB_NEED_BYTES ((size_t)12582912 * 2)                   // fallback: QKV only

typedef short s16x8 __attribute__((ext_vector_type(8)));
typedef float f32x16 __attribute__((ext_vector_type(16)));
typedef unsigned short u16x4 __attribute__((ext_vector_type(4)));

union FragU {
    s16x8 v;
    unsigned int u[4];
    unsigned short h[8];
};

static __device__ __forceinline__ unsigned int pack2_bf16(float a, float b) {
    __hip_bfloat162 h2 = __float22bfloat162_rn(float2{a, b});
    union { __hip_bfloat162 h; unsigned int u; } cv;
    cv.h = h2;
    return cv.u;
}

static __device__ __forceinline__ unsigned short to_bf16(float a) {
    __hip_bfloat16 h = __float2bfloat16(a);
    union { __hip_bfloat16 h; unsigned short u; } cv;
    cv.h = h;
    return cv.u;
}

// log2(e)/64 : folds the 1/hd score scale and exp->exp2 into Q
#define Q_PRESCALE 0.022542110f
// log2(1e8)/128
#define FREQ_L2 0.20762050593046f

// ---------------------------------------------------------------------------
// fp32 -> bf16 convert + reorder into MFMA frag-tile layout:
//   dst[tile(row>>5)][kc(k>>4)][lane(hi*32+row&31)][j(k&7)],  hi=(k>>3)&1
// Each thread: 8 consecutive channels of one row. grid (nrows/4, 1, 3).
// ---------------------------------------------------------------------------
__global__ __launch_bounds__(256) void conv_frag(
    const float* __restrict__ a, const float* __restrict__ b,
    const float* __restrict__ c, unsigned short* __restrict__ dst,
    int zstride)
{
    const int z = blockIdx.z;
    const float* src = (z == 0) ? a : ((z == 1) ? b : c);
    const size_t base = ((size_t)blockIdx.x * 256 + threadIdx.x) * 8;
    const int row = (int)(base >> 9);
    const int k   = (int)(base & 511);
    const int kc  = k >> 4;
    const int hi  = (k >> 3) & 1;

    const float4* p = (const float4*)(src + base);
    float4 x0 = p[0], x1 = p[1];
    FragU f;
    f.u[0] = pack2_bf16(x0.x, x0.y);
    f.u[1] = pack2_bf16(x0.z, x0.w);
    f.u[2] = pack2_bf16(x1.x, x1.y);
    f.u[3] = pack2_bf16(x1.z, x1.w);
    const size_t off = (size_t)z * zstride + (size_t)(row >> 5) * 16384
                     + kc * 512 + (hi * 32 + (row & 31)) * 8;
    *(s16x8*)(dst + off) = f.v;
}

// ---------------------------------------------------------------------------
// Shared epilogue for the QKV GEMM.
// z<2 (transposed GEMM, C = o x s): lane quad = 4 consecutive channels ->
//   in-lane rotary, u16x4 store into Q/K frag-tile layout (per bh):
//   off = (s>>5)*2048 + ((k6>>4))*512 + (((k6>>3)&1)*32 + (s&31))*8 + (k6&7)
// z==2 (normal GEMM, C = s x o): lane quad = 4 consecutive tokens ->
//   u16x4 store into V^T frag-tile layout (per bh):
//   off = (s>>5)*2048 + (d>>5)*1024 + ((s>>4)&1)*512 + (((s>>3)&1)*32+(d&31))*8 + (s&7)
// ---------------------------------------------------------------------------
static __device__ __forceinline__ void qkv_epilogue(
    int z, const f32x16 acc[2][2], int m0, int n0, int c31, int hi,
    const float* __restrict__ bias, unsigned short* __restrict__ dst_base)
{
    if (z < 2) {
        unsigned short* dst = dst_base + (size_t)z * 4194304;
        #pragma unroll
        for (int nt = 0; nt < 2; ++nt) {
            const int s_g = n0 + nt * 32 + c31;       // global token
            const int b   = s_g >> 12;
            const int s   = s_g & 4095;
            const float pos0 = (float)(s >> 6);
            const float pos1 = (float)(s & 63);
            #pragma unroll
            for (int mt = 0; mt < 2; ++mt) {
                #pragma unroll
                for (int g = 0; g < 4; ++g) {
                    const int o_b = m0 + mt * 32 + 8 * g + 4 * hi;   // 4-aligned channel quad
                    const float4 bb = *(const float4*)(bias + o_b);
                    float v0 = acc[mt][nt][4 * g + 0] + bb.x;
                    float v1 = acc[mt][nt][4 * g + 1] + bb.y;
                    float v2 = acc[mt][nt][4 * g + 2] + bb.z;
                    float v3 = acc[mt][nt][4 * g + 3] + bb.w;
                    const float fr0 = exp2f(-(float)(o_b >> 2) * FREQ_L2);
                    const float fr1 = exp2f(-(float)((o_b + 2) >> 2) * FREQ_L2); // == fr0
                    float sn0, cs0, sn1, cs1;
                    __sincosf(pos0 * fr0, &sn0, &cs0);
                    __sincosf(pos1 * fr1, &sn1, &cs1);
                    float r0 = v0 * cs0 - v1 * sn0;
                    float r1 = v0 * sn0 + v1 * cs0;
                    float r2 = v2 * cs1 - v3 * sn1;
                    float r3 = v2 * sn1 + v3 * cs1;
                    if (z == 0) { r0 *= Q_PRESCALE; r1 *= Q_PRESCALE; r2 *= Q_PRESCALE; r3 *= Q_PRESCALE; }
                    const int bh = b * NH + (o_b >> 6);
                    const int k6 = o_b & 63;
                    u16x4 pk;
                    pk.x = to_bf16(r0); pk.y = to_bf16(r1);
                    pk.z = to_bf16(r2); pk.w = to_bf16(r3);
                    const size_t off = (size_t)bh * 262144 + (s >> 5) * 2048
                                     + (k6 >> 4) * 512 + (((k6 >> 3) & 1) * 32 + (s & 31)) * 8 + (k6 & 7);
                    *(u16x4*)(dst + off) = pk;
                }
            }
        }
    } else {
        unsigned short* dst = dst_base + 8388608;
        #pragma unroll
        for (int nt = 0; nt < 2; ++nt) {
            const int o  = n0 + nt * 32 + c31;        // channel (per lane)
            const float bv_ = bias[o];
            const int d = o & 63, hh = o >> 6;
            #pragma unroll
            for (int mt = 0; mt < 2; ++mt) {
                #pragma unroll
                for (int g = 0; g < 4; ++g) {
                    const int s_b = m0 + mt * 32 + 8 * g + 4 * hi;  // 4-aligned token quad
                    const int b = s_b >> 12;
                    const int s = s_b & 4095;
                    const int bh = b * NH + hh;
                    u16x4 pk;
                    pk.x = to_bf16(acc[mt][nt][4 * g + 0] + bv_);
                    pk.y = to_bf16(acc[mt][nt][4 * g + 1] + bv_);
                    pk.z = to_bf16(acc[mt][nt][4 * g + 2] + bv_);
                    pk.w = to_bf16(acc[mt][nt][4 * g + 3] + bv_);
                    const size_t off = (size_t)bh * 262144 + (s >> 5) * 2048 + (d >> 5) * 1024
                                     + ((s >> 4) & 1) * 512 + (((s >> 3) & 1) * 32 + (d & 31)) * 8 + (s & 7);
                    *(u16x4*)(dst + off) = pk;
                }
            }
        }
    }
}

// ---------------------------------------------------------------------------
// Kernel 1: QKV projection GEMM from frag-tile bf16 operands (dense 1KB loads).
// z<2: C^T = W x X^T (m=channels, n=tokens). z==2: C = X x W^T (m=tokens).
// grid (64, 4, 3), block 256; 128x128 block tile, 4 waves x (2x2 of 32x32).
// ---------------------------------------------------------------------------
__global__ __launch_bounds__(256) void qkv_gemm_rope(
    const unsigned short* __restrict__ xf, const unsigned short* __restrict__ wf,
    const float* __restrict__ bq, const float* __restrict__ bk,
    const float* __restrict__ bv, unsigned short* __restrict__ dst_base)
{
    const int z = blockIdx.z;
    const float* bias = (z == 0) ? bq : ((z == 1) ? bk : bv);
    const unsigned short* X = xf + (size_t)z * 4194304;
    const unsigned short* W = wf + (size_t)z * 262144;

    const int tid  = threadIdx.x;
    const int wv   = tid >> 6;
    const int lane = tid & 63;
    const int c31  = lane & 31;
    const int hi   = lane >> 5;
    const int wm   = wv >> 1, wn = wv & 1;

    int m0, n0;
    const unsigned short *A, *B;
    if (z < 2) {  // transposed: A = W (channels), B = X (tokens)
        m0 = blockIdx.y * 128 + wm * 64;
        n0 = blockIdx.x * 128 + wn * 64;
        A = W; B = X;
    } else {      // normal: A = X (tokens), B = W (channels)
        m0 = blockIdx.x * 128 + wm * 64;
        n0 = blockIdx.y * 128 + wn * 64;
        A = X; B = W;
    }

    const unsigned short* ap0 = A + (size_t)(m0 >> 5) * 16384 + lane * 8;
    const unsigned short* ap1 = ap0 + 16384;
    const unsigned short* bp0 = B + (size_t)(n0 >> 5) * 16384 + lane * 8;
    const unsigned short* bp1 = bp0 + 16384;

    f32x16 acc[2][2];
    #pragma unroll
    for (int a = 0; a < 2; ++a)
    #pragma unroll
    for (int b = 0; b < 2; ++b)
    #pragma unroll
    for (int r = 0; r < 16; ++r) acc[a][b][r] = 0.f;

    #pragma unroll 4
    for (int kc = 0; kc < 32; ++kc) {
        const int ko = kc * 512;
        s16x8 a0 = *(const s16x8*)(ap0 + ko);
        s16x8 a1 = *(const s16x8*)(ap1 + ko);
        s16x8 b0 = *(const s16x8*)(bp0 + ko);
        s16x8 b1 = *(const s16x8*)(bp1 + ko);
        acc[0][0] = __builtin_amdgcn_mfma_f32_32x32x16_bf16(a0, b0, acc[0][0], 0, 0, 0);
        acc[0][1] = __builtin_amdgcn_mfma_f32_32x32x16_bf16(a0, b1, acc[0][1], 0, 0, 0);
        acc[1][0] = __builtin_amdgcn_mfma_f32_32x32x16_bf16(a1, b0, acc[1][0], 0, 0, 0);
        acc[1][1] = __builtin_amdgcn_mfma_f32_32x32x16_bf16(a1, b1, acc[1][1], 0, 0, 0);
    }

    qkv_epilogue(z, acc, m0, n0, c31, hi, bias, dst_base);
}

// ---------------------------------------------------------------------------
// Kernel 1 fallback (fp32 inputs directly; used only if ws too small).
// ---------------------------------------------------------------------------
__global__ __launch_bounds__(256) void qkv_rope_f32(
    const float* __restrict__ q_in, const float* __restrict__ k_in,
    const float* __restrict__ v_in,
    const float* __restrict__ Wq, const float* __restrict__ bq,
    const float* __restrict__ Wk, const float* __restrict__ bk,
    const float* __restrict__ Wv, const float* __restrict__ bv,
    unsigned short* __restrict__ dst_base)
{
    const int z = blockIdx.z;
    const float* Xr = (z == 0) ? q_in : ((z == 1) ? k_in : v_in);
    const float* Wr = (z == 0) ? Wq   : ((z == 1) ? Wk   : Wv);
    const float* bias = (z == 0) ? bq : ((z == 1) ? bk : bv);

    const int tid  = threadIdx.x;
    const int wv   = tid >> 6;
    const int lane = tid & 63;
    const int c31  = lane & 31;
    const int hi   = lane >> 5;
    const int wm   = wv >> 1, wn = wv & 1;

    int m0, n0;
    const float *A, *B;
    if (z < 2) { m0 = blockIdx.y * 128 + wm * 64; n0 = blockIdx.x * 128 + wn * 64; A = Wr; B = Xr; }
    else       { m0 = blockIdx.x * 128 + wm * 64; n0 = blockIdx.y * 128 + wn * 64; A = Xr; B = Wr; }

    f32x16 acc[2][2];
    #pragma unroll
    for (int a = 0; a < 2; ++a)
    #pragma unroll
    for (int b = 0; b < 2; ++b)
    #pragma unroll
    for (int r = 0; r < 16; ++r) acc[a][b][r] = 0.f;

    for (int kc = 0; kc < 32; ++kc) {
        const int kofs = kc * 16 + hi * 8;
        FragU a_f[2], b_f[2];
        #pragma unroll
        for (int mt = 0; mt < 2; ++mt) {
            const float4* p = (const float4*)(A + (size_t)(m0 + mt * 32 + c31) * 512 + kofs);
            float4 x0 = p[0], x1 = p[1];
            a_f[mt].u[0] = pack2_bf16(x0.x, x0.y);
            a_f[mt].u[1] = pack2_bf16(x0.z, x0.w);
            a_f[mt].u[2] = pack2_bf16(x1.x, x1.y);
            a_f[mt].u[3] = pack2_bf16(x1.z, x1.w);
        }
        #pragma unroll
        for (int nt = 0; nt < 2; ++nt) {
            const float4* p = (const float4*)(B + (size_t)(n0 + nt * 32 + c31) * 512 + kofs);
            float4 x0 = p[0], x1 = p[1];
            b_f[nt].u[0] = pack2_bf16(x0.x, x0.y);
            b_f[nt].u[1] = pack2_bf16(x0.z, x0.w);
            b_f[nt].u[2] = pack2_bf16(x1.x, x1.y);
            b_f[nt].u[3] = pack2_bf16(x1.z, x1.w);
        }
        #pragma unroll
        for (int mt = 0; mt < 2; ++mt)
        #pragma unroll
        for (int nt = 0; nt < 2; ++nt)
            acc[mt][nt] = __builtin_amdgcn_mfma_f32_32x32x16_bf16(
                a_f[mt].v, b_f[nt].v, acc[mt][nt], 0, 0, 0);
    }

    qkv_epilogue(z, acc, m0, n0, c31, hi, bias, dst_base);
}

// ---------------------------------------------------------------------------
// Kernel 2: flash attention (S^T trick). All operand loads are dense 1KB
// wave-loads from frag-tile layouts. No LDS/barriers in main loop.
// grid (64, 16), block 256.
// ---------------------------------------------------------------------------
__global__ __launch_bounds__(256, 3) void flash_attn_st(
    const unsigned short* __restrict__ qkv, float* __restrict__ out)
{
    __shared__ __align__(16) unsigned char smem[33792];
    float* sOb = (float*)smem;                                 // 2 * 4096 floats (post-loop)
    float* sL  = (float*)(smem + 32768);                       // 4*2*32 floats

    const int tid  = threadIdx.x;
    const int wv   = tid >> 6;
    const int lane = tid & 63;
    const int c31  = lane & 31;
    const int hi   = lane >> 5;
    const int q0   = blockIdx.x * 64;
    const int bh   = blockIdx.y;

    const unsigned short* Qb  = qkv + (size_t)bh * 262144;
    const unsigned short* Kb  = qkv + (size_t)4194304 + (size_t)bh * 262144;
    const unsigned short* Vtb = qkv + (size_t)8388608 + (size_t)bh * 262144;

    // Q B-frags from frag-tile layout
    s16x8 qf[2][4];
    #pragma unroll
    for (int qt = 0; qt < 2; ++qt)
    #pragma unroll
    for (int kc = 0; kc < 4; ++kc)
        qf[qt][kc] = *(const s16x8*)(Qb + (size_t)((q0 >> 5) + qt) * 2048 + kc * 512 + lane * 8);

    f32x16 o_acc[2][2];                   // [d-tile][q-tile], O^T layout
    #pragma unroll
    for (int a = 0; a < 2; ++a)
    #pragma unroll
    for (int b = 0; b < 2; ++b)
    #pragma unroll
    for (int r = 0; r < 16; ++r) o_acc[a][b][r] = 0.f;
    float l_acc[2] = {0.f, 0.f};

    const unsigned short* kp = Kb  + (size_t)wv * 2048 + lane * 8;   // += 8192/iter
    const unsigned short* vp = Vtb + (size_t)wv * 2048 + lane * 8;   // += 8192/iter

    // preload K A-frags for iter 0
    s16x8 ka[4];
    #pragma unroll
    for (int kc = 0; kc < 4; ++kc)
        ka[kc] = *(const s16x8*)(kp + kc * 512);

    for (int it = 0; it < 32; ++it) {
        // ---- issue V^T A-frag loads now; consumed at iter end ----
        s16x8 va[2][2];
        va[0][0] = *(const s16x8*)(vp);
        va[0][1] = *(const s16x8*)(vp + 512);
        va[1][0] = *(const s16x8*)(vp + 1024);
        va[1][1] = *(const s16x8*)(vp + 1536);
        vp += 8192;

        unsigned int up[2][8];

        // ---- qt0: S^T = K * Q^T, exp2, pack ----
        {
            f32x16 st;
            #pragma unroll
            for (int r = 0; r < 16; ++r) st[r] = 0.f;
            #pragma unroll
            for (int kc = 0; kc < 4; ++kc)
                st = __builtin_amdgcn_mfma_f32_32x32x16_bf16(ka[kc], qf[0][kc], st, 0, 0, 0);
            float ls0 = 0.f, ls1 = 0.f;
            #pragma unroll
            for (int qq = 0; qq < 8; ++qq) {
                float p0 = __builtin_amdgcn_exp2f(st[2 * qq]);
                float p1 = __builtin_amdgcn_exp2f(st[2 * qq + 1]);
                ls0 += p0; ls1 += p1;
                up[0][qq] = pack2_bf16(p0, p1);
            }
            l_acc[0] += ls0 + ls1;
        }

        // ---- qt1: S^T MFMAs (last use of ka) ----
        f32x16 st;
        #pragma unroll
        for (int r = 0; r < 16; ++r) st[r] = 0.f;
        #pragma unroll
        for (int kc = 0; kc < 4; ++kc)
            st = __builtin_amdgcn_mfma_f32_32x32x16_bf16(ka[kc], qf[1][kc], st, 0, 0, 0);

        // ---- prefetch next iter's K into the SAME ka regs ----
        kp += 8192;
        if (it < 31) {
            #pragma unroll
            for (int kc = 0; kc < 4; ++kc)
                ka[kc] = *(const s16x8*)(kp + kc * 512);
        }

        // ---- qt1 exp2 + pack ----
        {
            float ls0 = 0.f, ls1 = 0.f;
            #pragma unroll
            for (int qq = 0; qq < 8; ++qq) {
                float p0 = __builtin_amdgcn_exp2f(st[2 * qq]);
                float p1 = __builtin_amdgcn_exp2f(st[2 * qq + 1]);
                ls0 += p0; ls1 += p1;
                up[1][qq] = pack2_bf16(p0, p1);
            }
            l_acc[1] += ls0 + ls1;
        }

        // ---- O^T += V^T * P^T ; P^T B-frag assembled via shfl_xor(32) ----
        #pragma unroll
        for (int qt = 0; qt < 2; ++qt) {
            #pragma unroll
            for (int k2 = 0; k2 < 2; ++k2) {
                const unsigned int a0 = up[qt][4 * k2 + 0];
                const unsigned int a1 = up[qt][4 * k2 + 1];
                const unsigned int a2 = up[qt][4 * k2 + 2];
                const unsigned int a3 = up[qt][4 * k2 + 3];
                const unsigned int s0 = (unsigned int)__shfl_xor((int)(hi ? a0 : a2), 32);
                const unsigned int s1 = (unsigned int)__shfl_xor((int)(hi ? a1 : a3), 32);
                FragU pb;
                pb.u[0] = hi ? s0 : a0;
                pb.u[1] = hi ? s1 : a1;
                pb.u[2] = hi ? a2 : s0;
                pb.u[3] = hi ? a3 : s1;
                #pragma unroll
                for (int dt = 0; dt < 2; ++dt)
                    o_acc[dt][qt] = __builtin_amdgcn_mfma_f32_32x32x16_bf16(
                        va[dt][k2], pb.v, o_acc[dt][qt], 0, 0, 0);
            }
        }
    }

    // ---- merge partials across the 4 waves ----
    {
        float l0 = l_acc[0] + __shfl_xor(l_acc[0], 32);
        float l1 = l_acc[1] + __shfl_xor(l_acc[1], 32);
        if (lane < 32) {
            sL[(wv * 2 + 0) * 32 + lane] = l0;
            sL[(wv * 2 + 1) * 32 + lane] = l1;
        }
    }
    __syncthreads();

    if (wv == 1 || wv == 2) {
        float* buf = sOb + (wv - 1) * 4096;
        #pragma unroll
        for (int dt = 0; dt < 2; ++dt)
        #pragma unroll
        for (int qt = 0; qt < 2; ++qt)
        #pragma unroll
        for (int r = 0; r < 16; ++r) {
            const int d = dt * 32 + (r & 3) + 8 * (r >> 2) + 4 * hi;
            buf[d * 64 + qt * 32 + c31] = o_acc[dt][qt][r];
        }
    }
    __syncthreads();
    if (wv == 0 || wv == 3) {
        const float* buf = sOb + ((wv == 0) ? 0 : 4096);
        #pragma unroll
        for (int dt = 0; dt < 2; ++dt)
        #pragma unroll
        for (int qt = 0; qt < 2; ++qt)
        #pragma unroll
        for (int r = 0; r < 16; ++r) {
            const int d = dt * 32 + (r & 3) + 8 * (r >> 2) + 4 * hi;
            o_acc[dt][qt][r] += buf[d * 64 + qt * 32 + c31];
        }
    }
    __syncthreads();
    if (wv == 3) {
        #pragma unroll
        for (int dt = 0; dt < 2; ++dt)
        #pragma unroll
        for (int qt = 0; qt < 2; ++qt)
        #pragma unroll
        for (int r = 0; r < 16; ++r) {
            const int d = dt * 32 + (r & 3) + 8 * (r >> 2) + 4 * hi;
            sOb[d * 64 + qt * 32 + c31] = o_acc[dt][qt][r];
        }
    }
    __syncthreads();
    if (wv == 0) {
        #pragma unroll
        for (int dt = 0; dt < 2; ++dt)
        #pragma unroll
        for (int qt = 0; qt < 2; ++qt)
        #pragma unroll
        for (int r = 0; r < 16; ++r) {
            const int d = dt * 32 + (r & 3) + 8 * (r >> 2) + 4 * hi;
            o_acc[dt][qt][r] += sOb[d * 64 + qt * 32 + c31];
        }
        const int b  = bh >> 3;
        const int hh = bh & 7;
        #pragma unroll
        for (int qt = 0; qt < 2; ++qt) {
            const float lsum = sL[(0 * 2 + qt) * 32 + c31] + sL[(1 * 2 + qt) * 32 + c31]
                             + sL[(2 * 2 + qt) * 32 + c31] + sL[(3 * 2 + qt) * 32 + c31];
            const float rinv = 1.f / lsum;
            const int s = q0 + qt * 32 + c31;
            float* orow = out + ((size_t)b * S_LEN + s) * 512 + hh * 64;
            #pragma unroll
            for (int dt = 0; dt < 2; ++dt) {
                #pragma unroll
                for (int g = 0; g < 4; ++g) {
                    float4 vv;
                    vv.x = o_acc[dt][qt][4 * g + 0] * rinv;
                    vv.y = o_acc[dt][qt][4 * g + 1] * rinv;
                    vv.z = o_acc[dt][qt][4 * g + 2] * rinv;
                    vv.w = o_acc[dt][qt][4 * g + 3] * rinv;
                    *(float4*)(orow + dt * 32 + 8 * g + 4 * hi) = vv;
                }
            }
        }
    }
}

extern "C" void kernel_launch(void* const* d_in, const int* in_sizes, int n_in,
                              void* d_out, int out_size, void* d_ws, size_t ws_size,
                              hipStream_t stream) {
    (void)in_sizes; (void)n_in; (void)out_size;
    const float* q_in = (const float*)d_in[0];
    const float* k_in = (const float*)d_in[1];
    const float* v_in = (const float*)d_in[2];
    const float* Wq   = (const float*)d_in[3];
    const float* bq   = (const float*)d_in[4];
    const float* Wk   = (const float*)d_in[5];
    const float* bk   = (const float*)d_in[6];
    const float* Wv   = (const float*)d_in[7];
    const float* bv   = (const float*)d_in[8];
    unsigned short* ws = (unsigned short*)d_ws;
    float* out = (float*)d_out;

    if (ws_size >= WS_NEED_BYTES) {
        conv_frag<<<dim3(2048, 1, 3), 256, 0, stream>>>(q_in, k_in, v_in, ws + XFRAG_OFF, 4194304);
        conv_frag<<<dim3(128, 1, 3), 256, 0, stream>>>(Wq, Wk, Wv, ws + WFRAG_OFF, 262144);
        qkv_gemm_rope<<<dim3(64, 4, 3), 256, 0, stream>>>(
            ws + XFRAG_OFF, ws + WFRAG_OFF, bq, bk, bv, ws + QKV_OFF);
        flash_attn_st<<<dim3(64, 16), 256, 0, stream>>>(ws + QKV_OFF, out);
    } else {
        qkv_rope_f32<<<dim3(64, 4, 3), 256, 0, stream>>>(
            q_in, k_in, v_in, Wq, bq, Wk, bk, Wv, bv, ws);
        flash_attn_st<<<dim3(64, 16), 256, 0, stream>>>(ws, out);
    }
}

// Round 6
// 236.148 us; speedup vs baseline: 1.5383x; 1.0032x over previous
//
#include <hip/hip_runtime.h>
#include <hip/hip_bf16.h>

#define S_LEN 4096
#define HDIM  64
#define NH    8

// ws layout (ushort element offsets), big-ws path:
//   XFRAG: 3 * 4194304   bf16 X (q,k,v inputs) in frag-tile layout
//   WFRAG: 3 * 262144    bf16 W in frag-tile layout
//   QKV:   Q(4194304) K(4194304) Vt(4194304), per-bh 262144, frag-tile layouts
#define XFRAG_OFF 0
#define WFRAG_OFF 12582912
#define QKV_OFF   13369344
#define WS_NEED_BYTES ((size_t)(13369344 + 12582912) * 2)      // 51,904,512
#define FB_NEED_BYTES ((size_t)12582912 * 2)                   // fallback: QKV only

typedef short s16x8 __attribute__((ext_vector_type(8)));
typedef float f32x16 __attribute__((ext_vector_type(16)));
typedef unsigned short u16x4 __attribute__((ext_vector_type(4)));

union FragU {
    s16x8 v;
    unsigned int u[4];
    unsigned short h[8];
};

static __device__ __forceinline__ unsigned int pack2_bf16(float a, float b) {
    __hip_bfloat162 h2 = __float22bfloat162_rn(float2{a, b});
    union { __hip_bfloat162 h; unsigned int u; } cv;
    cv.h = h2;
    return cv.u;
}

static __device__ __forceinline__ unsigned short to_bf16(float a) {
    __hip_bfloat16 h = __float2bfloat16(a);
    union { __hip_bfloat16 h; unsigned short u; } cv;
    cv.h = h;
    return cv.u;
}

// log2(e)/64 : folds the 1/hd score scale and exp->exp2 into Q
#define Q_PRESCALE 0.022542110f
// log2(1e8)/128
#define FREQ_L2 0.20762050593046f

// ---------------------------------------------------------------------------
// fp32 -> bf16 convert + reorder into MFMA frag-tile layout, DENSE WRITES.
// One launch covers X (bx<256) and W (bx>=256). Per block: one 32-row slab,
// wave w handles kc = w*8..w*8+7 (ALL 32 kc across 4 waves — r5 bug was *4);
// lane l = hi*32+row; writes 1KB dense/wave.
// grid (272, 1, 3), block 256.
// ---------------------------------------------------------------------------
__global__ __launch_bounds__(256) void conv_frag2(
    const float* __restrict__ qx, const float* __restrict__ kx,
    const float* __restrict__ vx,
    const float* __restrict__ Wq, const float* __restrict__ Wk,
    const float* __restrict__ Wv,
    unsigned short* __restrict__ xdst, unsigned short* __restrict__ wdst)
{
    const int z  = blockIdx.z;
    const int bx = blockIdx.x;
    const int tid  = threadIdx.x;
    const int wv   = tid >> 6;
    const int lane = tid & 63;
    const int row  = lane & 31;
    const int hi   = lane >> 5;

    const float* src;
    unsigned short* dst;
    if (bx < 256) {
        src = ((z == 0) ? qx : ((z == 1) ? kx : vx)) + (size_t)(bx * 32 + row) * 512 + hi * 8;
        dst = xdst + (size_t)z * 4194304 + (size_t)bx * 16384;
    } else {
        const int s = bx - 256;
        src = ((z == 0) ? Wq : ((z == 1) ? Wk : Wv)) + (size_t)(s * 32 + row) * 512 + hi * 8;
        dst = wdst + (size_t)z * 262144 + (size_t)s * 16384;
    }

    #pragma unroll
    for (int i = 0; i < 8; ++i) {
        const int kc = wv * 8 + i;
        const float4* p = (const float4*)(src + kc * 16);
        float4 x0 = p[0], x1 = p[1];
        FragU f;
        f.u[0] = pack2_bf16(x0.x, x0.y);
        f.u[1] = pack2_bf16(x0.z, x0.w);
        f.u[2] = pack2_bf16(x1.x, x1.y);
        f.u[3] = pack2_bf16(x1.z, x1.w);
        *(s16x8*)(dst + kc * 512 + lane * 8) = f.v;
    }
}

// ---------------------------------------------------------------------------
// Shared epilogue for the QKV GEMM (unchanged from r4, verified).
// ---------------------------------------------------------------------------
static __device__ __forceinline__ void qkv_epilogue(
    int z, const f32x16 acc[2][2], int m0, int n0, int c31, int hi,
    const float* __restrict__ bias, unsigned short* __restrict__ dst_base)
{
    if (z < 2) {
        unsigned short* dst = dst_base + (size_t)z * 4194304;
        #pragma unroll
        for (int nt = 0; nt < 2; ++nt) {
            const int s_g = n0 + nt * 32 + c31;       // global token
            const int b   = s_g >> 12;
            const int s   = s_g & 4095;
            const float pos0 = (float)(s >> 6);
            const float pos1 = (float)(s & 63);
            #pragma unroll
            for (int mt = 0; mt < 2; ++mt) {
                #pragma unroll
                for (int g = 0; g < 4; ++g) {
                    const int o_b = m0 + mt * 32 + 8 * g + 4 * hi;   // 4-aligned channel quad
                    const float4 bb = *(const float4*)(bias + o_b);
                    float v0 = acc[mt][nt][4 * g + 0] + bb.x;
                    float v1 = acc[mt][nt][4 * g + 1] + bb.y;
                    float v2 = acc[mt][nt][4 * g + 2] + bb.z;
                    float v3 = acc[mt][nt][4 * g + 3] + bb.w;
                    const float fr0 = exp2f(-(float)(o_b >> 2) * FREQ_L2);
                    float sn0, cs0, sn1, cs1;
                    __sincosf(pos0 * fr0, &sn0, &cs0);
                    __sincosf(pos1 * fr0, &sn1, &cs1);
                    float r0 = v0 * cs0 - v1 * sn0;
                    float r1 = v0 * sn0 + v1 * cs0;
                    float r2 = v2 * cs1 - v3 * sn1;
                    float r3 = v2 * sn1 + v3 * cs1;
                    if (z == 0) { r0 *= Q_PRESCALE; r1 *= Q_PRESCALE; r2 *= Q_PRESCALE; r3 *= Q_PRESCALE; }
                    const int bh = b * NH + (o_b >> 6);
                    const int k6 = o_b & 63;
                    u16x4 pk;
                    pk.x = to_bf16(r0); pk.y = to_bf16(r1);
                    pk.z = to_bf16(r2); pk.w = to_bf16(r3);
                    const size_t off = (size_t)bh * 262144 + (s >> 5) * 2048
                                     + (k6 >> 4) * 512 + (((k6 >> 3) & 1) * 32 + (s & 31)) * 8 + (k6 & 7);
                    *(u16x4*)(dst + off) = pk;
                }
            }
        }
    } else {
        unsigned short* dst = dst_base + 8388608;
        #pragma unroll
        for (int nt = 0; nt < 2; ++nt) {
            const int o  = n0 + nt * 32 + c31;        // channel (per lane)
            const float bv_ = bias[o];
            const int d = o & 63, hh = o >> 6;
            #pragma unroll
            for (int mt = 0; mt < 2; ++mt) {
                #pragma unroll
                for (int g = 0; g < 4; ++g) {
                    const int s_b = m0 + mt * 32 + 8 * g + 4 * hi;  // 4-aligned token quad
                    const int b = s_b >> 12;
                    const int s = s_b & 4095;
                    const int bh = b * NH + hh;
                    u16x4 pk;
                    pk.x = to_bf16(acc[mt][nt][4 * g + 0] + bv_);
                    pk.y = to_bf16(acc[mt][nt][4 * g + 1] + bv_);
                    pk.z = to_bf16(acc[mt][nt][4 * g + 2] + bv_);
                    pk.w = to_bf16(acc[mt][nt][4 * g + 3] + bv_);
                    const size_t off = (size_t)bh * 262144 + (s >> 5) * 2048 + (d >> 5) * 1024
                                     + ((s >> 4) & 1) * 512 + (((s >> 3) & 1) * 32 + (d & 31)) * 8 + (s & 7);
                    *(u16x4*)(dst + off) = pk;
                }
            }
        }
    }
}

// ---------------------------------------------------------------------------
// Kernel 1: QKV projection GEMM from frag-tile bf16 operands (dense 1KB loads).
// grid (64, 4, 3), block 256 (unchanged from r4, verified).
// ---------------------------------------------------------------------------
__global__ __launch_bounds__(256) void qkv_gemm_rope(
    const unsigned short* __restrict__ xf, const unsigned short* __restrict__ wf,
    const float* __restrict__ bq, const float* __restrict__ bk,
    const float* __restrict__ bv, unsigned short* __restrict__ dst_base)
{
    const int z = blockIdx.z;
    const float* bias = (z == 0) ? bq : ((z == 1) ? bk : bv);
    const unsigned short* X = xf + (size_t)z * 4194304;
    const unsigned short* W = wf + (size_t)z * 262144;

    const int tid  = threadIdx.x;
    const int wv   = tid >> 6;
    const int lane = tid & 63;
    const int c31  = lane & 31;
    const int hi   = lane >> 5;
    const int wm   = wv >> 1, wn = wv & 1;

    int m0, n0;
    const unsigned short *A, *B;
    if (z < 2) {  // transposed: A = W (channels), B = X (tokens)
        m0 = blockIdx.y * 128 + wm * 64;
        n0 = blockIdx.x * 128 + wn * 64;
        A = W; B = X;
    } else {      // normal: A = X (tokens), B = W (channels)
        m0 = blockIdx.x * 128 + wm * 64;
        n0 = blockIdx.y * 128 + wn * 64;
        A = X; B = W;
    }

    const unsigned short* ap0 = A + (size_t)(m0 >> 5) * 16384 + lane * 8;
    const unsigned short* ap1 = ap0 + 16384;
    const unsigned short* bp0 = B + (size_t)(n0 >> 5) * 16384 + lane * 8;
    const unsigned short* bp1 = bp0 + 16384;

    f32x16 acc[2][2];
    #pragma unroll
    for (int a = 0; a < 2; ++a)
    #pragma unroll
    for (int b = 0; b < 2; ++b)
    #pragma unroll
    for (int r = 0; r < 16; ++r) acc[a][b][r] = 0.f;

    #pragma unroll 4
    for (int kc = 0; kc < 32; ++kc) {
        const int ko = kc * 512;
        s16x8 a0 = *(const s16x8*)(ap0 + ko);
        s16x8 a1 = *(const s16x8*)(ap1 + ko);
        s16x8 b0 = *(const s16x8*)(bp0 + ko);
        s16x8 b1 = *(const s16x8*)(bp1 + ko);
        acc[0][0] = __builtin_amdgcn_mfma_f32_32x32x16_bf16(a0, b0, acc[0][0], 0, 0, 0);
        acc[0][1] = __builtin_amdgcn_mfma_f32_32x32x16_bf16(a0, b1, acc[0][1], 0, 0, 0);
        acc[1][0] = __builtin_amdgcn_mfma_f32_32x32x16_bf16(a1, b0, acc[1][0], 0, 0, 0);
        acc[1][1] = __builtin_amdgcn_mfma_f32_32x32x16_bf16(a1, b1, acc[1][1], 0, 0, 0);
    }

    qkv_epilogue(z, acc, m0, n0, c31, hi, bias, dst_base);
}

// ---------------------------------------------------------------------------
// Kernel 1 fallback (fp32 inputs directly; used only if ws too small).
// ---------------------------------------------------------------------------
__global__ __launch_bounds__(256) void qkv_rope_f32(
    const float* __restrict__ q_in, const float* __restrict__ k_in,
    const float* __restrict__ v_in,
    const float* __restrict__ Wq, const float* __restrict__ bq,
    const float* __restrict__ Wk, const float* __restrict__ bk,
    const float* __restrict__ Wv, const float* __restrict__ bv,
    unsigned short* __restrict__ dst_base)
{
    const int z = blockIdx.z;
    const float* Xr = (z == 0) ? q_in : ((z == 1) ? k_in : v_in);
    const float* Wr = (z == 0) ? Wq   : ((z == 1) ? Wk   : Wv);
    const float* bias = (z == 0) ? bq : ((z == 1) ? bk : bv);

    const int tid  = threadIdx.x;
    const int wv   = tid >> 6;
    const int lane = tid & 63;
    const int c31  = lane & 31;
    const int hi   = lane >> 5;
    const int wm   = wv >> 1, wn = wv & 1;

    int m0, n0;
    const float *A, *B;
    if (z < 2) { m0 = blockIdx.y * 128 + wm * 64; n0 = blockIdx.x * 128 + wn * 64; A = Wr; B = Xr; }
    else       { m0 = blockIdx.x * 128 + wm * 64; n0 = blockIdx.y * 128 + wn * 64; A = Xr; B = Wr; }

    f32x16 acc[2][2];
    #pragma unroll
    for (int a = 0; a < 2; ++a)
    #pragma unroll
    for (int b = 0; b < 2; ++b)
    #pragma unroll
    for (int r = 0; r < 16; ++r) acc[a][b][r] = 0.f;

    for (int kc = 0; kc < 32; ++kc) {
        const int kofs = kc * 16 + hi * 8;
        FragU a_f[2], b_f[2];
        #pragma unroll
        for (int mt = 0; mt < 2; ++mt) {
            const float4* p = (const float4*)(A + (size_t)(m0 + mt * 32 + c31) * 512 + kofs);
            float4 x0 = p[0], x1 = p[1];
            a_f[mt].u[0] = pack2_bf16(x0.x, x0.y);
            a_f[mt].u[1] = pack2_bf16(x0.z, x0.w);
            a_f[mt].u[2] = pack2_bf16(x1.x, x1.y);
            a_f[mt].u[3] = pack2_bf16(x1.z, x1.w);
        }
        #pragma unroll
        for (int nt = 0; nt < 2; ++nt) {
            const float4* p = (const float4*)(B + (size_t)(n0 + nt * 32 + c31) * 512 + kofs);
            float4 x0 = p[0], x1 = p[1];
            b_f[nt].u[0] = pack2_bf16(x0.x, x0.y);
            b_f[nt].u[1] = pack2_bf16(x0.z, x0.w);
            b_f[nt].u[2] = pack2_bf16(x1.x, x1.y);
            b_f[nt].u[3] = pack2_bf16(x1.z, x1.w);
        }
        #pragma unroll
        for (int mt = 0; mt < 2; ++mt)
        #pragma unroll
        for (int nt = 0; nt < 2; ++nt)
            acc[mt][nt] = __builtin_amdgcn_mfma_f32_32x32x16_bf16(
                a_f[mt].v, b_f[nt].v, acc[mt][nt], 0, 0, 0);
    }

    qkv_epilogue(z, acc, m0, n0, c31, hi, bias, dst_base);
}

// ---------------------------------------------------------------------------
// Kernel 2: flash attention (S^T trick), 4-waves/SIMD re-tiling:
//   wave = (qs, ks): q-subtile 32 (o_acc 32 AGPR), kv split 2-way (64 iters)
//   Q frags in LDS (8 KB, shared), K prefetch into same regs, dense loads.
// grid (64, 16), block 256, __launch_bounds__(256,4).
// ---------------------------------------------------------------------------
__global__ __launch_bounds__(256, 4) void flash_attn_st(
    const unsigned short* __restrict__ qkv, float* __restrict__ out)
{
    __shared__ __align__(16) unsigned char smem[8192 + 16384 + 256];
    unsigned short* sQ = (unsigned short*)smem;            // [chunk(qs*4+kc)][lane][8]
    float* sOb = (float*)(smem + 8192);                    // [qs][d(64)][q(32)]
    float* sL  = (float*)(smem + 8192 + 16384);            // [qs][32]

    const int tid  = threadIdx.x;
    const int wv   = tid >> 6;
    const int lane = tid & 63;
    const int c31  = lane & 31;
    const int hi   = lane >> 5;
    const int qs   = wv >> 1;
    const int ks   = wv & 1;
    const int q0   = blockIdx.x * 64;
    const int bh   = blockIdx.y;

    const unsigned short* Qb  = qkv + (size_t)bh * 262144;
    const unsigned short* Kb  = qkv + (size_t)4194304 + (size_t)bh * 262144;
    const unsigned short* Vtb = qkv + (size_t)8388608 + (size_t)bh * 262144;

    // cooperative Q -> LDS (8 chunks x 64 entries x 16B)
    #pragma unroll
    for (int i = 0; i < 2; ++i) {
        const int idx   = tid + i * 256;
        const int chunk = idx >> 6;
        const int ln    = idx & 63;
        *(s16x8*)(sQ + chunk * 512 + ln * 8) =
            *(const s16x8*)(Qb + (size_t)((q0 >> 5) + (chunk >> 2)) * 2048 + (chunk & 3) * 512 + ln * 8);
    }
    __syncthreads();

    const unsigned short* sQw = sQ + qs * 2048 + lane * 8;

    f32x16 o_acc[2];                      // [d-tile], O^T layout (rows=d, cols=q)
    #pragma unroll
    for (int dt = 0; dt < 2; ++dt)
    #pragma unroll
    for (int r = 0; r < 16; ++r) o_acc[dt][r] = 0.f;
    float l_acc = 0.f;

    const unsigned short* kp = Kb  + (size_t)ks * 2048 + lane * 8;   // += 4096/iter
    const unsigned short* vp = Vtb + (size_t)ks * 2048 + lane * 8;   // += 4096/iter

    // preload K A-frags for iter 0
    s16x8 ka[4];
    #pragma unroll
    for (int kc = 0; kc < 4; ++kc)
        ka[kc] = *(const s16x8*)(kp + kc * 512);

    for (int it = 0; it < 64; ++it) {
        // ---- issue V^T A-frag loads now; consumed at iter end ----
        s16x8 va[2][2];
        va[0][0] = *(const s16x8*)(vp);
        va[0][1] = *(const s16x8*)(vp + 512);
        va[1][0] = *(const s16x8*)(vp + 1024);
        va[1][1] = *(const s16x8*)(vp + 1536);
        vp += 4096;

        // ---- S^T = K * Q^T (Q B-frags from LDS) ----
        f32x16 st;
        #pragma unroll
        for (int r = 0; r < 16; ++r) st[r] = 0.f;
        #pragma unroll
        for (int kc = 0; kc < 4; ++kc) {
            s16x8 qf = *(const s16x8*)(sQw + kc * 512);
            st = __builtin_amdgcn_mfma_f32_32x32x16_bf16(ka[kc], qf, st, 0, 0, 0);
        }

        // ---- prefetch next iter's K into the SAME ka regs ----
        kp += 4096;
        if (it < 63) {
            #pragma unroll
            for (int kc = 0; kc < 4; ++kc)
                ka[kc] = *(const s16x8*)(kp + kc * 512);
        }

        // ---- exp2 + pack ----
        unsigned int up[8];
        {
            float ls0 = 0.f, ls1 = 0.f;
            #pragma unroll
            for (int qq = 0; qq < 8; ++qq) {
                float p0 = __builtin_amdgcn_exp2f(st[2 * qq]);
                float p1 = __builtin_amdgcn_exp2f(st[2 * qq + 1]);
                ls0 += p0; ls1 += p1;
                up[qq] = pack2_bf16(p0, p1);
            }
            l_acc += ls0 + ls1;
        }

        // ---- O^T += V^T * P^T ; P^T B-frag assembled via shfl_xor(32) ----
        #pragma unroll
        for (int k2 = 0; k2 < 2; ++k2) {
            const unsigned int a0 = up[4 * k2 + 0];
            const unsigned int a1 = up[4 * k2 + 1];
            const unsigned int a2 = up[4 * k2 + 2];
            const unsigned int a3 = up[4 * k2 + 3];
            const unsigned int s0 = (unsigned int)__shfl_xor((int)(hi ? a0 : a2), 32);
            const unsigned int s1 = (unsigned int)__shfl_xor((int)(hi ? a1 : a3), 32);
            FragU pb;
            pb.u[0] = hi ? s0 : a0;
            pb.u[1] = hi ? s1 : a1;
            pb.u[2] = hi ? a2 : s0;
            pb.u[3] = hi ? a3 : s1;
            #pragma unroll
            for (int dt = 0; dt < 2; ++dt)
                o_acc[dt] = __builtin_amdgcn_mfma_f32_32x32x16_bf16(
                    va[dt][k2], pb.v, o_acc[dt], 0, 0, 0);
        }
    }

    // ---- 2-way kv merge per q-subtile ----
    const float lw = l_acc + __shfl_xor(l_acc, 32);
    if (ks == 1) {
        if (lane < 32) sL[qs * 32 + lane] = lw;
        #pragma unroll
        for (int dt = 0; dt < 2; ++dt)
        #pragma unroll
        for (int r = 0; r < 16; ++r) {
            const int d = dt * 32 + (r & 3) + 8 * (r >> 2) + 4 * hi;
            sOb[qs * 2048 + d * 32 + c31] = o_acc[dt][r];
        }
    }
    __syncthreads();
    if (ks == 0) {
        #pragma unroll
        for (int dt = 0; dt < 2; ++dt)
        #pragma unroll
        for (int r = 0; r < 16; ++r) {
            const int d = dt * 32 + (r & 3) + 8 * (r >> 2) + 4 * hi;
            o_acc[dt][r] += sOb[qs * 2048 + d * 32 + c31];
        }
        const float rinv = 1.f / (lw + sL[qs * 32 + c31]);
        const int b  = bh >> 3;
        const int hh = bh & 7;
        const int s  = q0 + qs * 32 + c31;
        float* orow = out + ((size_t)b * S_LEN + s) * 512 + hh * 64;
        #pragma unroll
        for (int dt = 0; dt < 2; ++dt) {
            #pragma unroll
            for (int g = 0; g < 4; ++g) {
                float4 vv;
                vv.x = o_acc[dt][4 * g + 0] * rinv;
                vv.y = o_acc[dt][4 * g + 1] * rinv;
                vv.z = o_acc[dt][4 * g + 2] * rinv;
                vv.w = o_acc[dt][4 * g + 3] * rinv;
                *(float4*)(orow + dt * 32 + 8 * g + 4 * hi) = vv;
            }
        }
    }
}

extern "C" void kernel_launch(void* const* d_in, const int* in_sizes, int n_in,
                              void* d_out, int out_size, void* d_ws, size_t ws_size,
                              hipStream_t stream) {
    (void)in_sizes; (void)n_in; (void)out_size;
    const float* q_in = (const float*)d_in[0];
    const float* k_in = (const float*)d_in[1];
    const float* v_in = (const float*)d_in[2];
    const float* Wq   = (const float*)d_in[3];
    const float* bq   = (const float*)d_in[4];
    const float* Wk   = (const float*)d_in[5];
    const float* bk   = (const float*)d_in[6];
    const float* Wv   = (const float*)d_in[7];
    const float* bv   = (const float*)d_in[8];
    unsigned short* ws = (unsigned short*)d_ws;
    float* out = (float*)d_out;

    if (ws_size >= WS_NEED_BYTES) {
        conv_frag2<<<dim3(272, 1, 3), 256, 0, stream>>>(
            q_in, k_in, v_in, Wq, Wk, Wv, ws + XFRAG_OFF, ws + WFRAG_OFF);
        qkv_gemm_rope<<<dim3(64, 4, 3), 256, 0, stream>>>(
            ws + XFRAG_OFF, ws + WFRAG_OFF, bq, bk, bv, ws + QKV_OFF);
        flash_attn_st<<<dim3(64, 16), 256, 0, stream>>>(ws + QKV_OFF, out);
    } else {
        qkv_rope_f32<<<dim3(64, 4, 3), 256, 0, stream>>>(
            q_in, k_in, v_in, Wq, bq, Wk, bk, Wv, bv, ws);
        flash_attn_st<<<dim3(64, 16), 256, 0, stream>>>(ws, out);
    }
}

// Round 7
// 234.421 us; speedup vs baseline: 1.5496x; 1.0074x over previous
//
#include <hip/hip_runtime.h>
#include <hip/hip_bf16.h>

#define S_LEN 4096
#define HDIM  64
#define NH    8

// ws layout (ushort element offsets), big-ws path:
//   XFRAG: 3 * 4194304   bf16 X (q,k,v inputs) in frag-tile layout
//   WFRAG: 3 * 262144    bf16 W in frag-tile layout
//   QKV:   Q(4194304) K(4194304) Vt(4194304), per-bh 262144, frag-tile layouts
#define XFRAG_OFF 0
#define WFRAG_OFF 12582912
#define QKV_OFF   13369344
#define WS_NEED_BYTES ((size_t)(13369344 + 12582912) * 2)      // 51,904,512

typedef short s16x8 __attribute__((ext_vector_type(8)));
typedef float f32x16 __attribute__((ext_vector_type(16)));
typedef unsigned short u16x4 __attribute__((ext_vector_type(4)));

union FragU {
    s16x8 v;
    unsigned int u[4];
    unsigned short h[8];
};

static __device__ __forceinline__ unsigned int pack2_bf16(float a, float b) {
    __hip_bfloat162 h2 = __float22bfloat162_rn(float2{a, b});
    union { __hip_bfloat162 h; unsigned int u; } cv;
    cv.h = h2;
    return cv.u;
}

static __device__ __forceinline__ unsigned short to_bf16(float a) {
    __hip_bfloat16 h = __float2bfloat16(a);
    union { __hip_bfloat16 h; unsigned short u; } cv;
    cv.h = h;
    return cv.u;
}

// log2(e)/64 : folds the 1/hd score scale and exp->exp2 into Q
#define Q_PRESCALE 0.022542110f
// log2(1e8)/128
#define FREQ_L2 0.20762050593046f

// ---------------------------------------------------------------------------
// fp32 -> bf16 convert + reorder into MFMA frag-tile layout, LDS-staged so
// BOTH global reads and global writes are dense.
//   phase 1: wave w, iter i -> row r = w*8+i of the 32-row slab; lane covers
//            cols [8*lane, 8*lane+8): dense 2KB/wave reads. Convert, store to
//            LDS at skewed frag addr (kc*520 + lane'*8), lane'=(lane&1)*32+r.
//   phase 2: wave w copies kc = w*8..w*8+7: dense ds_read_b128 + dense 1KB
//            global writes.
// One launch covers X (bx<256) and W (bx>=256). grid (272,1,3), block 256.
// ---------------------------------------------------------------------------
__global__ __launch_bounds__(256) void conv_frag3(
    const float* __restrict__ qx, const float* __restrict__ kx,
    const float* __restrict__ vx,
    const float* __restrict__ Wq, const float* __restrict__ Wk,
    const float* __restrict__ Wv,
    unsigned short* __restrict__ xdst, unsigned short* __restrict__ wdst)
{
    __shared__ __align__(16) unsigned short slds[16640];   // 32*520 + pad

    const int z  = blockIdx.z;
    const int bx = blockIdx.x;
    const int tid  = threadIdx.x;
    const int w    = tid >> 6;
    const int lane = tid & 63;

    const float* src;
    unsigned short* dst;
    if (bx < 256) {
        src = ((z == 0) ? qx : ((z == 1) ? kx : vx)) + (size_t)bx * 32 * 512;
        dst = xdst + (size_t)z * 4194304 + (size_t)bx * 16384;
    } else {
        const int s = bx - 256;
        src = ((z == 0) ? Wq : ((z == 1) ? Wk : Wv)) + (size_t)s * 32 * 512;
        dst = wdst + (size_t)z * 262144 + (size_t)s * 16384;
    }

    // phase 1: dense reads, convert, LDS scatter (conflict-benign)
    #pragma unroll
    for (int i = 0; i < 8; ++i) {
        const int r = w * 8 + i;
        const float4* p = (const float4*)(src + (size_t)r * 512 + lane * 8);
        float4 x0 = p[0], x1 = p[1];
        FragU f;
        f.u[0] = pack2_bf16(x0.x, x0.y);
        f.u[1] = pack2_bf16(x0.z, x0.w);
        f.u[2] = pack2_bf16(x1.x, x1.y);
        f.u[3] = pack2_bf16(x1.z, x1.w);
        *(s16x8*)(slds + (lane >> 1) * 520 + ((lane & 1) * 32 + r) * 8) = f.v;
    }
    __syncthreads();

    // phase 2: dense LDS reads, dense global writes
    #pragma unroll
    for (int i = 0; i < 8; ++i) {
        const int kc = w * 8 + i;
        s16x8 v = *(const s16x8*)(slds + kc * 520 + lane * 8);
        *(s16x8*)(dst + kc * 512 + lane * 8) = v;
    }
}

// ---------------------------------------------------------------------------
// Shared epilogue for the QKV GEMM (unchanged, verified r4-r6).
// ---------------------------------------------------------------------------
static __device__ __forceinline__ void qkv_epilogue(
    int z, const f32x16 acc[2][2], int m0, int n0, int c31, int hi,
    const float* __restrict__ bias, unsigned short* __restrict__ dst_base)
{
    if (z < 2) {
        unsigned short* dst = dst_base + (size_t)z * 4194304;
        #pragma unroll
        for (int nt = 0; nt < 2; ++nt) {
            const int s_g = n0 + nt * 32 + c31;       // global token
            const int b   = s_g >> 12;
            const int s   = s_g & 4095;
            const float pos0 = (float)(s >> 6);
            const float pos1 = (float)(s & 63);
            #pragma unroll
            for (int mt = 0; mt < 2; ++mt) {
                #pragma unroll
                for (int g = 0; g < 4; ++g) {
                    const int o_b = m0 + mt * 32 + 8 * g + 4 * hi;   // 4-aligned channel quad
                    const float4 bb = *(const float4*)(bias + o_b);
                    float v0 = acc[mt][nt][4 * g + 0] + bb.x;
                    float v1 = acc[mt][nt][4 * g + 1] + bb.y;
                    float v2 = acc[mt][nt][4 * g + 2] + bb.z;
                    float v3 = acc[mt][nt][4 * g + 3] + bb.w;
                    const float fr0 = exp2f(-(float)(o_b >> 2) * FREQ_L2);
                    float sn0, cs0, sn1, cs1;
                    __sincosf(pos0 * fr0, &sn0, &cs0);
                    __sincosf(pos1 * fr0, &sn1, &cs1);
                    float r0 = v0 * cs0 - v1 * sn0;
                    float r1 = v0 * sn0 + v1 * cs0;
                    float r2 = v2 * cs1 - v3 * sn1;
                    float r3 = v2 * sn1 + v3 * cs1;
                    if (z == 0) { r0 *= Q_PRESCALE; r1 *= Q_PRESCALE; r2 *= Q_PRESCALE; r3 *= Q_PRESCALE; }
                    const int bh = b * NH + (o_b >> 6);
                    const int k6 = o_b & 63;
                    u16x4 pk;
                    pk.x = to_bf16(r0); pk.y = to_bf16(r1);
                    pk.z = to_bf16(r2); pk.w = to_bf16(r3);
                    const size_t off = (size_t)bh * 262144 + (s >> 5) * 2048
                                     + (k6 >> 4) * 512 + (((k6 >> 3) & 1) * 32 + (s & 31)) * 8 + (k6 & 7);
                    *(u16x4*)(dst + off) = pk;
                }
            }
        }
    } else {
        unsigned short* dst = dst_base + 8388608;
        #pragma unroll
        for (int nt = 0; nt < 2; ++nt) {
            const int o  = n0 + nt * 32 + c31;        // channel (per lane)
            const float bv_ = bias[o];
            const int d = o & 63, hh = o >> 6;
            #pragma unroll
            for (int mt = 0; mt < 2; ++mt) {
                #pragma unroll
                for (int g = 0; g < 4; ++g) {
                    const int s_b = m0 + mt * 32 + 8 * g + 4 * hi;  // 4-aligned token quad
                    const int b = s_b >> 12;
                    const int s = s_b & 4095;
                    const int bh = b * NH + hh;
                    u16x4 pk;
                    pk.x = to_bf16(acc[mt][nt][4 * g + 0] + bv_);
                    pk.y = to_bf16(acc[mt][nt][4 * g + 1] + bv_);
                    pk.z = to_bf16(acc[mt][nt][4 * g + 2] + bv_);
                    pk.w = to_bf16(acc[mt][nt][4 * g + 3] + bv_);
                    const size_t off = (size_t)bh * 262144 + (s >> 5) * 2048 + (d >> 5) * 1024
                                     + ((s >> 4) & 1) * 512 + (((s >> 3) & 1) * 32 + (d & 31)) * 8 + (s & 7);
                    *(u16x4*)(dst + off) = pk;
                }
            }
        }
    }
}

// ---------------------------------------------------------------------------
// Kernel 1: QKV projection GEMM from frag-tile bf16 operands (dense 1KB loads).
// grid (64, 4, 3), block 256 (unchanged, verified).
// ---------------------------------------------------------------------------
__global__ __launch_bounds__(256) void qkv_gemm_rope(
    const unsigned short* __restrict__ xf, const unsigned short* __restrict__ wf,
    const float* __restrict__ bq, const float* __restrict__ bk,
    const float* __restrict__ bv, unsigned short* __restrict__ dst_base)
{
    const int z = blockIdx.z;
    const float* bias = (z == 0) ? bq : ((z == 1) ? bk : bv);
    const unsigned short* X = xf + (size_t)z * 4194304;
    const unsigned short* W = wf + (size_t)z * 262144;

    const int tid  = threadIdx.x;
    const int wv   = tid >> 6;
    const int lane = tid & 63;
    const int c31  = lane & 31;
    const int hi   = lane >> 5;
    const int wm   = wv >> 1, wn = wv & 1;

    int m0, n0;
    const unsigned short *A, *B;
    if (z < 2) {  // transposed: A = W (channels), B = X (tokens)
        m0 = blockIdx.y * 128 + wm * 64;
        n0 = blockIdx.x * 128 + wn * 64;
        A = W; B = X;
    } else {      // normal: A = X (tokens), B = W (channels)
        m0 = blockIdx.x * 128 + wm * 64;
        n0 = blockIdx.y * 128 + wn * 64;
        A = X; B = W;
    }

    const unsigned short* ap0 = A + (size_t)(m0 >> 5) * 16384 + lane * 8;
    const unsigned short* ap1 = ap0 + 16384;
    const unsigned short* bp0 = B + (size_t)(n0 >> 5) * 16384 + lane * 8;
    const unsigned short* bp1 = bp0 + 16384;

    f32x16 acc[2][2];
    #pragma unroll
    for (int a = 0; a < 2; ++a)
    #pragma unroll
    for (int b = 0; b < 2; ++b)
    #pragma unroll
    for (int r = 0; r < 16; ++r) acc[a][b][r] = 0.f;

    #pragma unroll 4
    for (int kc = 0; kc < 32; ++kc) {
        const int ko = kc * 512;
        s16x8 a0 = *(const s16x8*)(ap0 + ko);
        s16x8 a1 = *(const s16x8*)(ap1 + ko);
        s16x8 b0 = *(const s16x8*)(bp0 + ko);
        s16x8 b1 = *(const s16x8*)(bp1 + ko);
        acc[0][0] = __builtin_amdgcn_mfma_f32_32x32x16_bf16(a0, b0, acc[0][0], 0, 0, 0);
        acc[0][1] = __builtin_amdgcn_mfma_f32_32x32x16_bf16(a0, b1, acc[0][1], 0, 0, 0);
        acc[1][0] = __builtin_amdgcn_mfma_f32_32x32x16_bf16(a1, b0, acc[1][0], 0, 0, 0);
        acc[1][1] = __builtin_amdgcn_mfma_f32_32x32x16_bf16(a1, b1, acc[1][1], 0, 0, 0);
    }

    qkv_epilogue(z, acc, m0, n0, c31, hi, bias, dst_base);
}

// ---------------------------------------------------------------------------
// Kernel 1 fallback (fp32 inputs directly; used only if ws too small).
// ---------------------------------------------------------------------------
__global__ __launch_bounds__(256) void qkv_rope_f32(
    const float* __restrict__ q_in, const float* __restrict__ k_in,
    const float* __restrict__ v_in,
    const float* __restrict__ Wq, const float* __restrict__ bq,
    const float* __restrict__ Wk, const float* __restrict__ bk,
    const float* __restrict__ Wv, const float* __restrict__ bv,
    unsigned short* __restrict__ dst_base)
{
    const int z = blockIdx.z;
    const float* Xr = (z == 0) ? q_in : ((z == 1) ? k_in : v_in);
    const float* Wr = (z == 0) ? Wq   : ((z == 1) ? Wk   : Wv);
    const float* bias = (z == 0) ? bq : ((z == 1) ? bk : bv);

    const int tid  = threadIdx.x;
    const int wv   = tid >> 6;
    const int lane = tid & 63;
    const int c31  = lane & 31;
    const int hi   = lane >> 5;
    const int wm   = wv >> 1, wn = wv & 1;

    int m0, n0;
    const float *A, *B;
    if (z < 2) { m0 = blockIdx.y * 128 + wm * 64; n0 = blockIdx.x * 128 + wn * 64; A = Wr; B = Xr; }
    else       { m0 = blockIdx.x * 128 + wm * 64; n0 = blockIdx.y * 128 + wn * 64; A = Xr; B = Wr; }

    f32x16 acc[2][2];
    #pragma unroll
    for (int a = 0; a < 2; ++a)
    #pragma unroll
    for (int b = 0; b < 2; ++b)
    #pragma unroll
    for (int r = 0; r < 16; ++r) acc[a][b][r] = 0.f;

    for (int kc = 0; kc < 32; ++kc) {
        const int kofs = kc * 16 + hi * 8;
        FragU a_f[2], b_f[2];
        #pragma unroll
        for (int mt = 0; mt < 2; ++mt) {
            const float4* p = (const float4*)(A + (size_t)(m0 + mt * 32 + c31) * 512 + kofs);
            float4 x0 = p[0], x1 = p[1];
            a_f[mt].u[0] = pack2_bf16(x0.x, x0.y);
            a_f[mt].u[1] = pack2_bf16(x0.z, x0.w);
            a_f[mt].u[2] = pack2_bf16(x1.x, x1.y);
            a_f[mt].u[3] = pack2_bf16(x1.z, x1.w);
        }
        #pragma unroll
        for (int nt = 0; nt < 2; ++nt) {
            const float4* p = (const float4*)(B + (size_t)(n0 + nt * 32 + c31) * 512 + kofs);
            float4 x0 = p[0], x1 = p[1];
            b_f[nt].u[0] = pack2_bf16(x0.x, x0.y);
            b_f[nt].u[1] = pack2_bf16(x0.z, x0.w);
            b_f[nt].u[2] = pack2_bf16(x1.x, x1.y);
            b_f[nt].u[3] = pack2_bf16(x1.z, x1.w);
        }
        #pragma unroll
        for (int mt = 0; mt < 2; ++mt)
        #pragma unroll
        for (int nt = 0; nt < 2; ++nt)
            acc[mt][nt] = __builtin_amdgcn_mfma_f32_32x32x16_bf16(
                a_f[mt].v, b_f[nt].v, acc[mt][nt], 0, 0, 0);
    }

    qkv_epilogue(z, acc, m0, n0, c31, hi, bias, dst_base);
}

// ---------------------------------------------------------------------------
// Kernel 2: flash attention (S^T trick), VALU-minimized:
//   - P packed by bf16 TRUNCATION (2 VALU ops/pair, no software RNE)
//   - l computed on the MFMA pipe via ones-A-frag x P^T (consistent with the
//     truncated numerator, so truncation bias cancels in O/l)
//   - wave = (qs, ks), Q in LDS, K prefetch into same regs, dense loads
// grid (64, 16), block 256, __launch_bounds__(256,4).
// ---------------------------------------------------------------------------
__global__ __launch_bounds__(256, 4) void flash_attn_st(
    const unsigned short* __restrict__ qkv, float* __restrict__ out)
{
    __shared__ __align__(16) unsigned char smem[8192 + 16384 + 256];
    unsigned short* sQ = (unsigned short*)smem;            // [chunk(qs*4+kc)][lane][8]
    float* sOb = (float*)(smem + 8192);                    // [qs][d(64)][q(32)]
    float* sL  = (float*)(smem + 8192 + 16384);            // [qs][32]

    const int tid  = threadIdx.x;
    const int wv   = tid >> 6;
    const int lane = tid & 63;
    const int c31  = lane & 31;
    const int hi   = lane >> 5;
    const int qs   = wv >> 1;
    const int ks   = wv & 1;
    const int q0   = blockIdx.x * 64;
    const int bh   = blockIdx.y;

    const unsigned short* Qb  = qkv + (size_t)bh * 262144;
    const unsigned short* Kb  = qkv + (size_t)4194304 + (size_t)bh * 262144;
    const unsigned short* Vtb = qkv + (size_t)8388608 + (size_t)bh * 262144;

    // cooperative Q -> LDS (8 chunks x 64 entries x 16B)
    #pragma unroll
    for (int i = 0; i < 2; ++i) {
        const int idx   = tid + i * 256;
        const int chunk = idx >> 6;
        const int ln    = idx & 63;
        *(s16x8*)(sQ + chunk * 512 + ln * 8) =
            *(const s16x8*)(Qb + (size_t)((q0 >> 5) + (chunk >> 2)) * 2048 + (chunk & 3) * 512 + ln * 8);
    }
    __syncthreads();

    const unsigned short* sQw = sQ + qs * 2048 + lane * 8;

    // ones A-frag (bf16 1.0) for the l-row MFMA
    FragU ones;
    ones.u[0] = 0x3F803F80u; ones.u[1] = 0x3F803F80u;
    ones.u[2] = 0x3F803F80u; ones.u[3] = 0x3F803F80u;

    f32x16 o_acc[2];                      // [d-tile], O^T layout (rows=d, cols=q)
    f32x16 l_frag;                        // all 16 rows identical = sum_kv P
    #pragma unroll
    for (int dt = 0; dt < 2; ++dt)
    #pragma unroll
    for (int r = 0; r < 16; ++r) o_acc[dt][r] = 0.f;
    #pragma unroll
    for (int r = 0; r < 16; ++r) l_frag[r] = 0.f;

    const unsigned short* kp = Kb  + (size_t)ks * 2048 + lane * 8;   // += 4096/iter
    const unsigned short* vp = Vtb + (size_t)ks * 2048 + lane * 8;   // += 4096/iter

    // preload K A-frags for iter 0
    s16x8 ka[4];
    #pragma unroll
    for (int kc = 0; kc < 4; ++kc)
        ka[kc] = *(const s16x8*)(kp + kc * 512);

    for (int it = 0; it < 64; ++it) {
        // ---- issue V^T A-frag loads now; consumed at iter end ----
        s16x8 va[2][2];
        va[0][0] = *(const s16x8*)(vp);
        va[0][1] = *(const s16x8*)(vp + 512);
        va[1][0] = *(const s16x8*)(vp + 1024);
        va[1][1] = *(const s16x8*)(vp + 1536);
        vp += 4096;

        // ---- S^T = K * Q^T (Q B-frags from LDS) ----
        f32x16 st;
        #pragma unroll
        for (int r = 0; r < 16; ++r) st[r] = 0.f;
        #pragma unroll
        for (int kc = 0; kc < 4; ++kc) {
            s16x8 qf = *(const s16x8*)(sQw + kc * 512);
            st = __builtin_amdgcn_mfma_f32_32x32x16_bf16(ka[kc], qf, st, 0, 0, 0);
        }

        // ---- prefetch next iter's K into the SAME ka regs ----
        kp += 4096;
        if (it < 63) {
            #pragma unroll
            for (int kc = 0; kc < 4; ++kc)
                ka[kc] = *(const s16x8*)(kp + kc * 512);
        }

        // ---- exp2 + truncation pack (no l accumulation in VALU) ----
        unsigned int up[8];
        #pragma unroll
        for (int qq = 0; qq < 8; ++qq) {
            const float p0 = __builtin_amdgcn_exp2f(st[2 * qq]);
            const float p1 = __builtin_amdgcn_exp2f(st[2 * qq + 1]);
            up[qq] = (__float_as_uint(p1) & 0xFFFF0000u) | (__float_as_uint(p0) >> 16);
        }

        // ---- O^T += V^T * P^T ; l += ones * P^T (MFMA pipe) ----
        #pragma unroll
        for (int k2 = 0; k2 < 2; ++k2) {
            const unsigned int a0 = up[4 * k2 + 0];
            const unsigned int a1 = up[4 * k2 + 1];
            const unsigned int a2 = up[4 * k2 + 2];
            const unsigned int a3 = up[4 * k2 + 3];
            const unsigned int s0 = (unsigned int)__shfl_xor((int)(hi ? a0 : a2), 32);
            const unsigned int s1 = (unsigned int)__shfl_xor((int)(hi ? a1 : a3), 32);
            FragU pb;
            pb.u[0] = hi ? s0 : a0;
            pb.u[1] = hi ? s1 : a1;
            pb.u[2] = hi ? a2 : s0;
            pb.u[3] = hi ? a3 : s1;
            #pragma unroll
            for (int dt = 0; dt < 2; ++dt)
                o_acc[dt] = __builtin_amdgcn_mfma_f32_32x32x16_bf16(
                    va[dt][k2], pb.v, o_acc[dt], 0, 0, 0);
            l_frag = __builtin_amdgcn_mfma_f32_32x32x16_bf16(ones.v, pb.v, l_frag, 0, 0, 0);
        }
    }

    // ---- 2-way kv merge per q-subtile (l rows all identical -> reg 0) ----
    const float lw = l_frag[0];
    if (ks == 1) {
        if (lane < 32) sL[qs * 32 + lane] = lw;
        #pragma unroll
        for (int dt = 0; dt < 2; ++dt)
        #pragma unroll
        for (int r = 0; r < 16; ++r) {
            const int d = dt * 32 + (r & 3) + 8 * (r >> 2) + 4 * hi;
            sOb[qs * 2048 + d * 32 + c31] = o_acc[dt][r];
        }
    }
    __syncthreads();
    if (ks == 0) {
        #pragma unroll
        for (int dt = 0; dt < 2; ++dt)
        #pragma unroll
        for (int r = 0; r < 16; ++r) {
            const int d = dt * 32 + (r & 3) + 8 * (r >> 2) + 4 * hi;
            o_acc[dt][r] += sOb[qs * 2048 + d * 32 + c31];
        }
        const float rinv = 1.f / (lw + sL[qs * 32 + c31]);
        const int b  = bh >> 3;
        const int hh = bh & 7;
        const int s  = q0 + qs * 32 + c31;
        float* orow = out + ((size_t)b * S_LEN + s) * 512 + hh * 64;
        #pragma unroll
        for (int dt = 0; dt < 2; ++dt) {
            #pragma unroll
            for (int g = 0; g < 4; ++g) {
                float4 vv;
                vv.x = o_acc[dt][4 * g + 0] * rinv;
                vv.y = o_acc[dt][4 * g + 1] * rinv;
                vv.z = o_acc[dt][4 * g + 2] * rinv;
                vv.w = o_acc[dt][4 * g + 3] * rinv;
                *(float4*)(orow + dt * 32 + 8 * g + 4 * hi) = vv;
            }
        }
    }
}

extern "C" void kernel_launch(void* const* d_in, const int* in_sizes, int n_in,
                              void* d_out, int out_size, void* d_ws, size_t ws_size,
                              hipStream_t stream) {
    (void)in_sizes; (void)n_in; (void)out_size;
    const float* q_in = (const float*)d_in[0];
    const float* k_in = (const float*)d_in[1];
    const float* v_in = (const float*)d_in[2];
    const float* Wq   = (const float*)d_in[3];
    const float* bq   = (const float*)d_in[4];
    const float* Wk   = (const float*)d_in[5];
    const float* bk   = (const float*)d_in[6];
    const float* Wv   = (const float*)d_in[7];
    const float* bv   = (const float*)d_in[8];
    unsigned short* ws = (unsigned short*)d_ws;
    float* out = (float*)d_out;

    if (ws_size >= WS_NEED_BYTES) {
        conv_frag3<<<dim3(272, 1, 3), 256, 0, stream>>>(
            q_in, k_in, v_in, Wq, Wk, Wv, ws + XFRAG_OFF, ws + WFRAG_OFF);
        qkv_gemm_rope<<<dim3(64, 4, 3), 256, 0, stream>>>(
            ws + XFRAG_OFF, ws + WFRAG_OFF, bq, bk, bv, ws + QKV_OFF);
        flash_attn_st<<<dim3(64, 16), 256, 0, stream>>>(ws + QKV_OFF, out);
    } else {
        qkv_rope_f32<<<dim3(64, 4, 3), 256, 0, stream>>>(
            q_in, k_in, v_in, Wq, bq, Wk, bk, Wv, bv, ws);
        flash_attn_st<<<dim3(64, 16), 256, 0, stream>>>(ws, out);
    }
}

// Round 8
// 218.975 us; speedup vs baseline: 1.6589x; 1.0705x over previous
//
#include <hip/hip_runtime.h>
#include <hip/hip_bf16.h>

#define S_LEN 4096
#define HDIM  64
#define NH    8

// ws layout (ushort element offsets), big-ws path:
//   XFRAG: 3 * 4194304   bf16 X (q,k,v inputs) in frag-tile layout
//   WFRAG: 3 * 262144    bf16 W in frag-tile layout
//   QKV:   Q(4194304) K(4194304) Vt(4194304), per-bh 262144, frag-tile layouts
#define XFRAG_OFF 0
#define WFRAG_OFF 12582912
#define QKV_OFF   13369344
#define WS_NEED_BYTES ((size_t)(13369344 + 12582912) * 2)      // 51,904,512

typedef short s16x8 __attribute__((ext_vector_type(8)));
typedef float f32x16 __attribute__((ext_vector_type(16)));
typedef unsigned short u16x4 __attribute__((ext_vector_type(4)));

union FragU {
    s16x8 v;
    unsigned int u[4];
    unsigned short h[8];
};

static __device__ __forceinline__ unsigned int pack2_bf16(float a, float b) {
    __hip_bfloat162 h2 = __float22bfloat162_rn(float2{a, b});
    union { __hip_bfloat162 h; unsigned int u; } cv;
    cv.h = h2;
    return cv.u;
}

static __device__ __forceinline__ unsigned short to_bf16(float a) {
    __hip_bfloat16 h = __float2bfloat16(a);
    union { __hip_bfloat16 h; unsigned short u; } cv;
    cv.h = h;
    return cv.u;
}

// log2(e)/64 : folds the 1/hd score scale and exp->exp2 into Q
#define Q_PRESCALE 0.022542110f
// log2(1e8)/128
#define FREQ_L2 0.20762050593046f

// ---------------------------------------------------------------------------
// fp32 -> bf16 convert + reorder into MFMA frag-tile layout, LDS-staged
// (dense global reads AND dense global writes). Unchanged from r7.
// grid (272,1,3), block 256.
// ---------------------------------------------------------------------------
__global__ __launch_bounds__(256) void conv_frag3(
    const float* __restrict__ qx, const float* __restrict__ kx,
    const float* __restrict__ vx,
    const float* __restrict__ Wq, const float* __restrict__ Wk,
    const float* __restrict__ Wv,
    unsigned short* __restrict__ xdst, unsigned short* __restrict__ wdst)
{
    __shared__ __align__(16) unsigned short slds[16640];   // 32*520 + pad

    const int z  = blockIdx.z;
    const int bx = blockIdx.x;
    const int tid  = threadIdx.x;
    const int w    = tid >> 6;
    const int lane = tid & 63;

    const float* src;
    unsigned short* dst;
    if (bx < 256) {
        src = ((z == 0) ? qx : ((z == 1) ? kx : vx)) + (size_t)bx * 32 * 512;
        dst = xdst + (size_t)z * 4194304 + (size_t)bx * 16384;
    } else {
        const int s = bx - 256;
        src = ((z == 0) ? Wq : ((z == 1) ? Wk : Wv)) + (size_t)s * 32 * 512;
        dst = wdst + (size_t)z * 262144 + (size_t)s * 16384;
    }

    #pragma unroll
    for (int i = 0; i < 8; ++i) {
        const int r = w * 8 + i;
        const float4* p = (const float4*)(src + (size_t)r * 512 + lane * 8);
        float4 x0 = p[0], x1 = p[1];
        FragU f;
        f.u[0] = pack2_bf16(x0.x, x0.y);
        f.u[1] = pack2_bf16(x0.z, x0.w);
        f.u[2] = pack2_bf16(x1.x, x1.y);
        f.u[3] = pack2_bf16(x1.z, x1.w);
        *(s16x8*)(slds + (lane >> 1) * 520 + ((lane & 1) * 32 + r) * 8) = f.v;
    }
    __syncthreads();

    #pragma unroll
    for (int i = 0; i < 8; ++i) {
        const int kc = w * 8 + i;
        s16x8 v = *(const s16x8*)(slds + kc * 520 + lane * 8);
        *(s16x8*)(dst + kc * 512 + lane * 8) = v;
    }
}

// ---------------------------------------------------------------------------
// Shared epilogue for the QKV GEMM (unchanged, verified r4-r7).
// ---------------------------------------------------------------------------
static __device__ __forceinline__ void qkv_epilogue(
    int z, const f32x16 acc[2][2], int m0, int n0, int c31, int hi,
    const float* __restrict__ bias, unsigned short* __restrict__ dst_base)
{
    if (z < 2) {
        unsigned short* dst = dst_base + (size_t)z * 4194304;
        #pragma unroll
        for (int nt = 0; nt < 2; ++nt) {
            const int s_g = n0 + nt * 32 + c31;       // global token
            const int b   = s_g >> 12;
            const int s   = s_g & 4095;
            const float pos0 = (float)(s >> 6);
            const float pos1 = (float)(s & 63);
            #pragma unroll
            for (int mt = 0; mt < 2; ++mt) {
                #pragma unroll
                for (int g = 0; g < 4; ++g) {
                    const int o_b = m0 + mt * 32 + 8 * g + 4 * hi;   // 4-aligned channel quad
                    const float4 bb = *(const float4*)(bias + o_b);
                    float v0 = acc[mt][nt][4 * g + 0] + bb.x;
                    float v1 = acc[mt][nt][4 * g + 1] + bb.y;
                    float v2 = acc[mt][nt][4 * g + 2] + bb.z;
                    float v3 = acc[mt][nt][4 * g + 3] + bb.w;
                    const float fr0 = exp2f(-(float)(o_b >> 2) * FREQ_L2);
                    float sn0, cs0, sn1, cs1;
                    __sincosf(pos0 * fr0, &sn0, &cs0);
                    __sincosf(pos1 * fr0, &sn1, &cs1);
                    float r0 = v0 * cs0 - v1 * sn0;
                    float r1 = v0 * sn0 + v1 * cs0;
                    float r2 = v2 * cs1 - v3 * sn1;
                    float r3 = v2 * sn1 + v3 * cs1;
                    if (z == 0) { r0 *= Q_PRESCALE; r1 *= Q_PRESCALE; r2 *= Q_PRESCALE; r3 *= Q_PRESCALE; }
                    const int bh = b * NH + (o_b >> 6);
                    const int k6 = o_b & 63;
                    u16x4 pk;
                    pk.x = to_bf16(r0); pk.y = to_bf16(r1);
                    pk.z = to_bf16(r2); pk.w = to_bf16(r3);
                    const size_t off = (size_t)bh * 262144 + (s >> 5) * 2048
                                     + (k6 >> 4) * 512 + (((k6 >> 3) & 1) * 32 + (s & 31)) * 8 + (k6 & 7);
                    *(u16x4*)(dst + off) = pk;
                }
            }
        }
    } else {
        unsigned short* dst = dst_base + 8388608;
        #pragma unroll
        for (int nt = 0; nt < 2; ++nt) {
            const int o  = n0 + nt * 32 + c31;        // channel (per lane)
            const float bv_ = bias[o];
            const int d = o & 63, hh = o >> 6;
            #pragma unroll
            for (int mt = 0; mt < 2; ++mt) {
                #pragma unroll
                for (int g = 0; g < 4; ++g) {
                    const int s_b = m0 + mt * 32 + 8 * g + 4 * hi;  // 4-aligned token quad
                    const int b = s_b >> 12;
                    const int s = s_b & 4095;
                    const int bh = b * NH + hh;
                    u16x4 pk;
                    pk.x = to_bf16(acc[mt][nt][4 * g + 0] + bv_);
                    pk.y = to_bf16(acc[mt][nt][4 * g + 1] + bv_);
                    pk.z = to_bf16(acc[mt][nt][4 * g + 2] + bv_);
                    pk.w = to_bf16(acc[mt][nt][4 * g + 3] + bv_);
                    const size_t off = (size_t)bh * 262144 + (s >> 5) * 2048 + (d >> 5) * 1024
                                     + ((s >> 4) & 1) * 512 + (((s >> 3) & 1) * 32 + (d & 31)) * 8 + (s & 7);
                    *(u16x4*)(dst + off) = pk;
                }
            }
        }
    }
}

// ---------------------------------------------------------------------------
// Kernel 1: QKV projection GEMM from frag-tile bf16 operands (unchanged).
// grid (64, 4, 3), block 256.
// ---------------------------------------------------------------------------
__global__ __launch_bounds__(256) void qkv_gemm_rope(
    const unsigned short* __restrict__ xf, const unsigned short* __restrict__ wf,
    const float* __restrict__ bq, const float* __restrict__ bk,
    const float* __restrict__ bv, unsigned short* __restrict__ dst_base)
{
    const int z = blockIdx.z;
    const float* bias = (z == 0) ? bq : ((z == 1) ? bk : bv);
    const unsigned short* X = xf + (size_t)z * 4194304;
    const unsigned short* W = wf + (size_t)z * 262144;

    const int tid  = threadIdx.x;
    const int wv   = tid >> 6;
    const int lane = tid & 63;
    const int c31  = lane & 31;
    const int hi   = lane >> 5;
    const int wm   = wv >> 1, wn = wv & 1;

    int m0, n0;
    const unsigned short *A, *B;
    if (z < 2) {  // transposed: A = W (channels), B = X (tokens)
        m0 = blockIdx.y * 128 + wm * 64;
        n0 = blockIdx.x * 128 + wn * 64;
        A = W; B = X;
    } else {      // normal: A = X (tokens), B = W (channels)
        m0 = blockIdx.x * 128 + wm * 64;
        n0 = blockIdx.y * 128 + wn * 64;
        A = X; B = W;
    }

    const unsigned short* ap0 = A + (size_t)(m0 >> 5) * 16384 + lane * 8;
    const unsigned short* ap1 = ap0 + 16384;
    const unsigned short* bp0 = B + (size_t)(n0 >> 5) * 16384 + lane * 8;
    const unsigned short* bp1 = bp0 + 16384;

    f32x16 acc[2][2];
    #pragma unroll
    for (int a = 0; a < 2; ++a)
    #pragma unroll
    for (int b = 0; b < 2; ++b)
    #pragma unroll
    for (int r = 0; r < 16; ++r) acc[a][b][r] = 0.f;

    #pragma unroll 4
    for (int kc = 0; kc < 32; ++kc) {
        const int ko = kc * 512;
        s16x8 a0 = *(const s16x8*)(ap0 + ko);
        s16x8 a1 = *(const s16x8*)(ap1 + ko);
        s16x8 b0 = *(const s16x8*)(bp0 + ko);
        s16x8 b1 = *(const s16x8*)(bp1 + ko);
        acc[0][0] = __builtin_amdgcn_mfma_f32_32x32x16_bf16(a0, b0, acc[0][0], 0, 0, 0);
        acc[0][1] = __builtin_amdgcn_mfma_f32_32x32x16_bf16(a0, b1, acc[0][1], 0, 0, 0);
        acc[1][0] = __builtin_amdgcn_mfma_f32_32x32x16_bf16(a1, b0, acc[1][0], 0, 0, 0);
        acc[1][1] = __builtin_amdgcn_mfma_f32_32x32x16_bf16(a1, b1, acc[1][1], 0, 0, 0);
    }

    qkv_epilogue(z, acc, m0, n0, c31, hi, bias, dst_base);
}

// ---------------------------------------------------------------------------
// Kernel 1 fallback (fp32 inputs directly; used only if ws too small).
// ---------------------------------------------------------------------------
__global__ __launch_bounds__(256) void qkv_rope_f32(
    const float* __restrict__ q_in, const float* __restrict__ k_in,
    const float* __restrict__ v_in,
    const float* __restrict__ Wq, const float* __restrict__ bq,
    const float* __restrict__ Wk, const float* __restrict__ bk,
    const float* __restrict__ Wv, const float* __restrict__ bv,
    unsigned short* __restrict__ dst_base)
{
    const int z = blockIdx.z;
    const float* Xr = (z == 0) ? q_in : ((z == 1) ? k_in : v_in);
    const float* Wr = (z == 0) ? Wq   : ((z == 1) ? Wk   : Wv);
    const float* bias = (z == 0) ? bq : ((z == 1) ? bk : bv);

    const int tid  = threadIdx.x;
    const int wv   = tid >> 6;
    const int lane = tid & 63;
    const int c31  = lane & 31;
    const int hi   = lane >> 5;
    const int wm   = wv >> 1, wn = wv & 1;

    int m0, n0;
    const float *A, *B;
    if (z < 2) { m0 = blockIdx.y * 128 + wm * 64; n0 = blockIdx.x * 128 + wn * 64; A = Wr; B = Xr; }
    else       { m0 = blockIdx.x * 128 + wm * 64; n0 = blockIdx.y * 128 + wn * 64; A = Xr; B = Wr; }

    f32x16 acc[2][2];
    #pragma unroll
    for (int a = 0; a < 2; ++a)
    #pragma unroll
    for (int b = 0; b < 2; ++b)
    #pragma unroll
    for (int r = 0; r < 16; ++r) acc[a][b][r] = 0.f;

    for (int kc = 0; kc < 32; ++kc) {
        const int kofs = kc * 16 + hi * 8;
        FragU a_f[2], b_f[2];
        #pragma unroll
        for (int mt = 0; mt < 2; ++mt) {
            const float4* p = (const float4*)(A + (size_t)(m0 + mt * 32 + c31) * 512 + kofs);
            float4 x0 = p[0], x1 = p[1];
            a_f[mt].u[0] = pack2_bf16(x0.x, x0.y);
            a_f[mt].u[1] = pack2_bf16(x0.z, x0.w);
            a_f[mt].u[2] = pack2_bf16(x1.x, x1.y);
            a_f[mt].u[3] = pack2_bf16(x1.z, x1.w);
        }
        #pragma unroll
        for (int nt = 0; nt < 2; ++nt) {
            const float4* p = (const float4*)(B + (size_t)(n0 + nt * 32 + c31) * 512 + kofs);
            float4 x0 = p[0], x1 = p[1];
            b_f[nt].u[0] = pack2_bf16(x0.x, x0.y);
            b_f[nt].u[1] = pack2_bf16(x0.z, x0.w);
            b_f[nt].u[2] = pack2_bf16(x1.x, x1.y);
            b_f[nt].u[3] = pack2_bf16(x1.z, x1.w);
        }
        #pragma unroll
        for (int mt = 0; mt < 2; ++mt)
        #pragma unroll
        for (int nt = 0; nt < 2; ++nt)
            acc[mt][nt] = __builtin_amdgcn_mfma_f32_32x32x16_bf16(
                a_f[mt].v, b_f[nt].v, acc[mt][nt], 0, 0, 0);
    }

    qkv_epilogue(z, acc, m0, n0, c31, hi, bias, dst_base);
}

// ---------------------------------------------------------------------------
// Kernel 2: flash attention (S^T trick), round-8 shape:
//   - 1-D grid, XCD swizzle: bh = id&15 (id%8 = bh%8 pins bh's K/V to 1 XCD L2)
//   - each wave: BOTH q-tiles (K/V loads amortized 2x), 4-way kv split
//   - in-order-issue-aware interleave: S^T(q0); S^T(q1); K-prefetch;
//     exp(q0); PV(q0); exp(q1); PV(q1) — VALU bursts always have queued MFMAs
//   - Q frags via LDS, l on VALU, RN pack (v_cvt_pk_bf16_f32)
// grid (1024), block 256, __launch_bounds__(256,3).
// ---------------------------------------------------------------------------
__global__ __launch_bounds__(256, 3) void flash_attn_st(
    const unsigned short* __restrict__ qkv, float* __restrict__ out)
{
    __shared__ __align__(16) unsigned char smem[8192 + 32768 + 1024];
    unsigned short* sQ = (unsigned short*)smem;            // 8 chunks x 64 x 8
    float* sOb = (float*)(smem + 8192);                    // 2 x 4096 floats
    float* sL  = (float*)(smem + 8192 + 32768);            // 4 waves x 2 qt x 32

    const int tid  = threadIdx.x;
    const int wv   = tid >> 6;       // kv-split index 0..3
    const int lane = tid & 63;
    const int c31  = lane & 31;
    const int hi   = lane >> 5;
    const int id   = blockIdx.x;
    const int bh   = id & 15;        // id % 8 == bh % 8  -> XCD-local K/V
    const int q0   = (id >> 4) * 64;

    const unsigned short* Qb  = qkv + (size_t)bh * 262144;
    const unsigned short* Kb  = qkv + (size_t)4194304 + (size_t)bh * 262144;
    const unsigned short* Vtb = qkv + (size_t)8388608 + (size_t)bh * 262144;

    // cooperative Q -> LDS (8 chunks x 64 entries x 16B)
    #pragma unroll
    for (int i = 0; i < 2; ++i) {
        const int idx   = tid + i * 256;
        const int chunk = idx >> 6;
        const int ln    = idx & 63;
        *(s16x8*)(sQ + chunk * 512 + ln * 8) =
            *(const s16x8*)(Qb + (size_t)((q0 >> 5) + (chunk >> 2)) * 2048 + (chunk & 3) * 512 + ln * 8);
    }
    __syncthreads();

    const unsigned short* sQ0 = sQ + lane * 8;          // q-tile 0, + kc*512
    const unsigned short* sQ1 = sQ + 2048 + lane * 8;   // q-tile 1

    f32x16 o_acc[2][2];                   // [d-tile][q-tile], O^T layout
    #pragma unroll
    for (int a = 0; a < 2; ++a)
    #pragma unroll
    for (int b = 0; b < 2; ++b)
    #pragma unroll
    for (int r = 0; r < 16; ++r) o_acc[a][b][r] = 0.f;
    float l_acc[2] = {0.f, 0.f};

    const unsigned short* kp = Kb  + (size_t)wv * 2048 + lane * 8;   // += 8192/iter
    const unsigned short* vp = Vtb + (size_t)wv * 2048 + lane * 8;   // += 8192/iter

    // preload K A-frags for iter 0
    s16x8 ka[4];
    #pragma unroll
    for (int kc = 0; kc < 4; ++kc)
        ka[kc] = *(const s16x8*)(kp + kc * 512);

    for (int it = 0; it < 32; ++it) {
        // ---- issue V^T A-frag loads now; consumed at PV ----
        s16x8 va[2][2];
        va[0][0] = *(const s16x8*)(vp);
        va[0][1] = *(const s16x8*)(vp + 512);
        va[1][0] = *(const s16x8*)(vp + 1024);
        va[1][1] = *(const s16x8*)(vp + 1536);
        vp += 8192;

        // ---- S^T(q0) then S^T(q1): both chains queued on the matrix pipe ----
        f32x16 st0, st1;
        #pragma unroll
        for (int r = 0; r < 16; ++r) { st0[r] = 0.f; st1[r] = 0.f; }
        #pragma unroll
        for (int kc = 0; kc < 4; ++kc) {
            s16x8 qf = *(const s16x8*)(sQ0 + kc * 512);
            st0 = __builtin_amdgcn_mfma_f32_32x32x16_bf16(ka[kc], qf, st0, 0, 0, 0);
        }
        #pragma unroll
        for (int kc = 0; kc < 4; ++kc) {
            s16x8 qf = *(const s16x8*)(sQ1 + kc * 512);
            st1 = __builtin_amdgcn_mfma_f32_32x32x16_bf16(ka[kc], qf, st1, 0, 0, 0);
        }

        // ---- prefetch next iter's K into the SAME ka regs (after last use) ----
        kp += 8192;
        if (it < 31) {
            #pragma unroll
            for (int kc = 0; kc < 4; ++kc)
                ka[kc] = *(const s16x8*)(kp + kc * 512);
        }

        // ---- q0: exp + pack + l (VALU, overlaps q1's queued S^T MFMAs) ----
        unsigned int up0[8];
        {
            float ls0 = 0.f, ls1 = 0.f;
            #pragma unroll
            for (int qq = 0; qq < 8; ++qq) {
                float p0 = __builtin_amdgcn_exp2f(st0[2 * qq]);
                float p1 = __builtin_amdgcn_exp2f(st0[2 * qq + 1]);
                ls0 += p0; ls1 += p1;
                up0[qq] = pack2_bf16(p0, p1);
            }
            l_acc[0] += ls0 + ls1;
        }

        // ---- PV(q0): queued on matrix pipe before q1's exp runs on VALU ----
        #pragma unroll
        for (int k2 = 0; k2 < 2; ++k2) {
            const unsigned int a0 = up0[4 * k2 + 0];
            const unsigned int a1 = up0[4 * k2 + 1];
            const unsigned int a2 = up0[4 * k2 + 2];
            const unsigned int a3 = up0[4 * k2 + 3];
            const unsigned int s0 = (unsigned int)__shfl_xor((int)(hi ? a0 : a2), 32);
            const unsigned int s1 = (unsigned int)__shfl_xor((int)(hi ? a1 : a3), 32);
            FragU pb;
            pb.u[0] = hi ? s0 : a0;
            pb.u[1] = hi ? s1 : a1;
            pb.u[2] = hi ? a2 : s0;
            pb.u[3] = hi ? a3 : s1;
            #pragma unroll
            for (int dt = 0; dt < 2; ++dt)
                o_acc[dt][0] = __builtin_amdgcn_mfma_f32_32x32x16_bf16(
                    va[dt][k2], pb.v, o_acc[dt][0], 0, 0, 0);
        }

        // ---- q1: exp + pack + l (VALU, overlaps PV(q0) MFMAs) ----
        unsigned int up1[8];
        {
            float ls0 = 0.f, ls1 = 0.f;
            #pragma unroll
            for (int qq = 0; qq < 8; ++qq) {
                float p0 = __builtin_amdgcn_exp2f(st1[2 * qq]);
                float p1 = __builtin_amdgcn_exp2f(st1[2 * qq + 1]);
                ls0 += p0; ls1 += p1;
                up1[qq] = pack2_bf16(p0, p1);
            }
            l_acc[1] += ls0 + ls1;
        }

        // ---- PV(q1) ----
        #pragma unroll
        for (int k2 = 0; k2 < 2; ++k2) {
            const unsigned int a0 = up1[4 * k2 + 0];
            const unsigned int a1 = up1[4 * k2 + 1];
            const unsigned int a2 = up1[4 * k2 + 2];
            const unsigned int a3 = up1[4 * k2 + 3];
            const unsigned int s0 = (unsigned int)__shfl_xor((int)(hi ? a0 : a2), 32);
            const unsigned int s1 = (unsigned int)__shfl_xor((int)(hi ? a1 : a3), 32);
            FragU pb;
            pb.u[0] = hi ? s0 : a0;
            pb.u[1] = hi ? s1 : a1;
            pb.u[2] = hi ? a2 : s0;
            pb.u[3] = hi ? a3 : s1;
            #pragma unroll
            for (int dt = 0; dt < 2; ++dt)
                o_acc[dt][1] = __builtin_amdgcn_mfma_f32_32x32x16_bf16(
                    va[dt][k2], pb.v, o_acc[dt][1], 0, 0, 0);
        }
    }

    // ---- merge partials across the 4 kv-split waves (r4-verified) ----
    {
        float l0 = l_acc[0] + __shfl_xor(l_acc[0], 32);
        float l1 = l_acc[1] + __shfl_xor(l_acc[1], 32);
        if (lane < 32) {
            sL[(wv * 2 + 0) * 32 + lane] = l0;
            sL[(wv * 2 + 1) * 32 + lane] = l1;
        }
    }
    __syncthreads();

    if (wv == 1 || wv == 2) {
        float* buf = sOb + (wv - 1) * 4096;
        #pragma unroll
        for (int dt = 0; dt < 2; ++dt)
        #pragma unroll
        for (int qt = 0; qt < 2; ++qt)
        #pragma unroll
        for (int r = 0; r < 16; ++r) {
            const int d = dt * 32 + (r & 3) + 8 * (r >> 2) + 4 * hi;
            buf[d * 64 + qt * 32 + c31] = o_acc[dt][qt][r];
        }
    }
    __syncthreads();
    if (wv == 0 || wv == 3) {
        const float* buf = sOb + ((wv == 0) ? 0 : 4096);
        #pragma unroll
        for (int dt = 0; dt < 2; ++dt)
        #pragma unroll
        for (int qt = 0; qt < 2; ++qt)
        #pragma unroll
        for (int r = 0; r < 16; ++r) {
            const int d = dt * 32 + (r & 3) + 8 * (r >> 2) + 4 * hi;
            o_acc[dt][qt][r] += buf[d * 64 + qt * 32 + c31];
        }
    }
    __syncthreads();
    if (wv == 3) {
        #pragma unroll
        for (int dt = 0; dt < 2; ++dt)
        #pragma unroll
        for (int qt = 0; qt < 2; ++qt)
        #pragma unroll
        for (int r = 0; r < 16; ++r) {
            const int d = dt * 32 + (r & 3) + 8 * (r >> 2) + 4 * hi;
            sOb[d * 64 + qt * 32 + c31] = o_acc[dt][qt][r];
        }
    }
    __syncthreads();
    if (wv == 0) {
        #pragma unroll
        for (int dt = 0; dt < 2; ++dt)
        #pragma unroll
        for (int qt = 0; qt < 2; ++qt)
        #pragma unroll
        for (int r = 0; r < 16; ++r) {
            const int d = dt * 32 + (r & 3) + 8 * (r >> 2) + 4 * hi;
            o_acc[dt][qt][r] += sOb[d * 64 + qt * 32 + c31];
        }
        const int b  = bh >> 3;
        const int hh = bh & 7;
        #pragma unroll
        for (int qt = 0; qt < 2; ++qt) {
            const float lsum = sL[(0 * 2 + qt) * 32 + c31] + sL[(1 * 2 + qt) * 32 + c31]
                             + sL[(2 * 2 + qt) * 32 + c31] + sL[(3 * 2 + qt) * 32 + c31];
            const float rinv = 1.f / lsum;
            const int s = q0 + qt * 32 + c31;
            float* orow = out + ((size_t)b * S_LEN + s) * 512 + hh * 64;
            #pragma unroll
            for (int dt = 0; dt < 2; ++dt) {
                #pragma unroll
                for (int g = 0; g < 4; ++g) {
                    float4 vv;
                    vv.x = o_acc[dt][qt][4 * g + 0] * rinv;
                    vv.y = o_acc[dt][qt][4 * g + 1] * rinv;
                    vv.z = o_acc[dt][qt][4 * g + 2] * rinv;
                    vv.w = o_acc[dt][qt][4 * g + 3] * rinv;
                    *(float4*)(orow + dt * 32 + 8 * g + 4 * hi) = vv;
                }
            }
        }
    }
}

extern "C" void kernel_launch(void* const* d_in, const int* in_sizes, int n_in,
                              void* d_out, int out_size, void* d_ws, size_t ws_size,
                              hipStream_t stream) {
    (void)in_sizes; (void)n_in; (void)out_size;
    const float* q_in = (const float*)d_in[0];
    const float* k_in = (const float*)d_in[1];
    const float* v_in = (const float*)d_in[2];
    const float* Wq   = (const float*)d_in[3];
    const float* bq   = (const float*)d_in[4];
    const float* Wk   = (const float*)d_in[5];
    const float* bk   = (const float*)d_in[6];
    const float* Wv   = (const float*)d_in[7];
    const float* bv   = (const float*)d_in[8];
    unsigned short* ws = (unsigned short*)d_ws;
    float* out = (float*)d_out;

    if (ws_size >= WS_NEED_BYTES) {
        conv_frag3<<<dim3(272, 1, 3), 256, 0, stream>>>(
            q_in, k_in, v_in, Wq, Wk, Wv, ws + XFRAG_OFF, ws + WFRAG_OFF);
        qkv_gemm_rope<<<dim3(64, 4, 3), 256, 0, stream>>>(
            ws + XFRAG_OFF, ws + WFRAG_OFF, bq, bk, bv, ws + QKV_OFF);
        flash_attn_st<<<dim3(1024), 256, 0, stream>>>(ws + QKV_OFF, out);
    } else {
        qkv_rope_f32<<<dim3(64, 4, 3), 256, 0, stream>>>(
            q_in, k_in, v_in, Wq, bq, Wk, bk, Wv, bv, ws);
        flash_attn_st<<<dim3(1024), 256, 0, stream>>>(ws, out);
    }
}